// Round 4
// baseline (24263.559 us; speedup 1.0000x reference)
//
#include <hip/hip_runtime.h>
#include <stdint.h>

// ---------------------------------------------------------------------------
// LEM-style noisy RNN. T=128 x DIV=10 sequential steps, B=256, H=256.
// k_recur: 16 WGs x 16 batch rows, 8 waves, 3 barriers/step.
//   Weight stream is the bottleneck (~1MB/WG/step through L1):
//   - Wz + th(j=0,1) cached in REGISTERS (loaded once)
//   - th(j=2) staged in LDS (64KB, parallel LDS pipe)
//   - remainder streamed from L2 (b128 global loads)
// ---------------------------------------------------------------------------

typedef __attribute__((ext_vector_type(8))) short bf16x8_t;
typedef __attribute__((ext_vector_type(4))) float f32x4_t;
typedef unsigned short u16;

#define R_LDS_BYTES 156160

__device__ __forceinline__ float bf2f(u16 b) {
  union { uint32_t u; float f; } v; v.u = ((uint32_t)b) << 16; return v.f;
}
__device__ __forceinline__ u16 f2bf(float f) {
  union { float f; uint32_t u; } v; v.f = f;
  uint32_t x = v.u;
  return (u16)((x + 0x7FFFu + ((x >> 16) & 1u)) >> 16);   // RNE
}
__device__ __forceinline__ f32x4_t mfma16(bf16x8_t a, bf16x8_t b, f32x4_t c) {
  return __builtin_amdgcn_mfma_f32_16x16x32_bf16(a, b, c, 0, 0, 0);
}
__device__ __forceinline__ float sigm(float x) { return 1.0f / (1.0f + __expf(-x)); }
__device__ __forceinline__ float tanh_f(float x) {
  float t = __expf(-2.0f * fabsf(x));
  float r = (1.0f - t) / (1.0f + t);
  return x < 0.0f ? -r : r;
}
// granule swizzle for LDS frag buffers (producer scatter vs consumer b128)
__device__ __forceinline__ int gsw(int g) { return g ^ ((g >> 3) & 7); }

// MFMA 16x16x32 bf16 A-frag K-position for lane l, elem e
__device__ __forceinline__ int fragK(int l, int e) {
  return ((l >> 4) << 2) + (e & 3) + ((e >> 2) << 4);
}

// ---- JAX threefry2x32 (20 rounds) ----
__device__ __forceinline__ void threefry(uint32_t k0, uint32_t k1, uint32_t x0, uint32_t x1,
                                         uint32_t* o0, uint32_t* o1) {
  uint32_t ks2 = k0 ^ k1 ^ 0x1BD11BDAu;
  x0 += k0; x1 += k1;
#define TFR(rot) { x0 += x1; x1 = (x1 << rot) | (x1 >> (32 - rot)); x1 ^= x0; }
  TFR(13) TFR(15) TFR(26) TFR(6)   x0 += k1;  x1 += ks2 + 1u;
  TFR(17) TFR(29) TFR(16) TFR(24)  x0 += ks2; x1 += k0 + 2u;
  TFR(13) TFR(15) TFR(26) TFR(6)   x0 += k0;  x1 += k1 + 3u;
  TFR(17) TFR(29) TFR(16) TFR(24)  x0 += k1;  x1 += ks2 + 4u;
  TFR(13) TFR(15) TFR(26) TFR(6)   x0 += ks2; x1 += k0 + 5u;
#undef TFR
  *o0 = x0; *o1 = x1;
}

// bits -> N(0,1), matches jax.random.normal f32 (XLA erfinv poly)
__device__ __forceinline__ float bits2normal(uint32_t bits) {
  union { uint32_t u; float f; } cv; cv.u = 0x3F800000u | (bits >> 9);
  float f = cv.f - 1.0f;
  float u = fmaf(f, 2.0f, -0.99999994f);
  u = fmaxf(u, -0.99999994f);
  float w = -log1pf(-u * u);
  float p;
  if (w < 5.0f) {
    w = w - 2.5f;
    p = 2.81022636e-08f;
    p = fmaf(p, w, 3.43273939e-07f);
    p = fmaf(p, w, -3.5233877e-06f);
    p = fmaf(p, w, -4.39150654e-06f);
    p = fmaf(p, w, 0.00021858087f);
    p = fmaf(p, w, -0.00125372503f);
    p = fmaf(p, w, -0.00417768164f);
    p = fmaf(p, w, 0.246640727f);
    p = fmaf(p, w, 1.50140941f);
  } else {
    w = sqrtf(w) - 3.0f;
    p = -0.000200214257f;
    p = fmaf(p, w, 0.000100950558f);
    p = fmaf(p, w, 0.00134934322f);
    p = fmaf(p, w, -0.00367342844f);
    p = fmaf(p, w, 0.00573950773f);
    p = fmaf(p, w, -0.0076224613f);
    p = fmaf(p, w, 0.00943887047f);
    p = fmaf(p, w, 1.00167406f);
    p = fmaf(p, w, 2.83297682f);
  }
  return 1.41421354f * p * u;
}

// ---------------------------------------------------------------------------
// prep: Wic = W_i @ W_c  (1024x256), bip = b_i + W_i @ b_c
__global__ void k_prep(const float* __restrict__ W_i, const float* __restrict__ W_c,
                       const float* __restrict__ b_i, const float* __restrict__ b_c,
                       float* __restrict__ Wic, float* __restrict__ bip) {
  __shared__ float wi[256];
  __shared__ float red[256];
  int o = blockIdx.x; int tid = threadIdx.x;
  wi[tid] = W_i[o * 256 + tid];
  __syncthreads();
  float acc = 0.f;
  for (int j = 0; j < 256; ++j) acc = fmaf(wi[j], W_c[j * 256 + tid], acc);
  Wic[(size_t)o * 256 + tid] = acc;
  red[tid] = wi[tid] * b_c[tid];
  __syncthreads();
  for (int s = 128; s > 0; s >>= 1) { if (tid < s) red[tid] += red[tid + s]; __syncthreads(); }
  if (tid == 0) bip[o] = b_i[o] + red[0];
}

// combined biases: bias(c) = base(c) + bh(c), bh = b_h[c] (c<512), b_h[c-256] (c>=768)
__global__ void k_bias(const float* __restrict__ b_i, const float* __restrict__ bip,
                       const float* __restrict__ b_h,
                       float* __restrict__ biasD0, float* __restrict__ biasDn) {
  int c = blockIdx.x * 256 + threadIdx.x;
  float bh = (c < 512) ? b_h[c] : (c >= 768 ? b_h[c - 256] : 0.f);
  biasD0[c] = b_i[c] + bh;
  biasDn[c] = bip[c] + bh;
}

// pack weights (row-major fp32 O x K) into B-fragment order, bf16.
__global__ void k_packw(const float* __restrict__ srcA, int rowsA, const float* __restrict__ srcB,
                        u16* __restrict__ dst, int O, int K) {
  int t = blockIdx.x * blockDim.x + threadIdx.x;
  int KK = K >> 5;
  int total = (O >> 4) * KK * 64;
  if (t >= total) return;
  int l = t & 63; int kk = (t >> 6) % KK; int to = t / (64 * KK);
  int n = (to << 4) | (l & 15);
  int kb = (kk << 5) + ((l >> 4) << 2);
  const float* src = (n < rowsA) ? (srcA + (size_t)n * K) : (srcB + (size_t)(n - rowsA) * K);
  u16 out[8];
#pragma unroll
  for (int e = 0; e < 8; ++e) out[e] = f2bf(src[kb + (e & 3) + ((e >> 2) << 4)]);
  *reinterpret_cast<uint4*>(dst + (size_t)t * 8) = *reinterpret_cast<const uint4*>(out);
}

// pack input chunk into A-fragment order (plain, global)
__global__ void k_packa(const float* __restrict__ inp, int t0, int Tcc, u16* __restrict__ dst) {
  int t = blockIdx.x * blockDim.x + threadIdx.x;
  int total = Tcc * 16 * 8 * 64;
  if (t >= total) return;
  int l = t & 63; int kk = (t >> 6) & 7; int mt = (t >> 9) & 15; int tl = t >> 13;
  int b = (mt << 4) | (l & 15);
  int kb = (kk << 5) + ((l >> 4) << 2);
  const float* src = inp + ((size_t)(t0 + tl) * 256 + b) * 256;
  u16 out[8];
#pragma unroll
  for (int e = 0; e < 8; ++e) out[e] = f2bf(src[kb + (e & 3) + ((e >> 2) << 4)]);
  *reinterpret_cast<uint4*>(dst + (size_t)t * 8) = *reinterpret_cast<const uint4*>(out);
}

// noise gen, JAX threefry partitionable: bits[i] = o0^o1, (o0,o1)=threefry(key, 0, i)
__global__ void k_gen(u16* __restrict__ Apack, int gstep0) {
  int sl = blockIdx.x >> 7;
  int tb = (blockIdx.x & 127) * 1024 + threadIdx.x;   // [0, 131072)
  __shared__ uint32_t kf[2];
  if (threadIdx.x == 0) {
    uint32_t o0, o1;
    threefry(0u, 1234u, 0u, (uint32_t)(gstep0 + sl), &o0, &o1);
    kf[0] = o0; kf[1] = o1;
  }
  __syncthreads();
  int e = tb & 7; int l = (tb >> 3) & 63; int kk = (tb >> 9) & 15; int mt = tb >> 13;
  int b = (mt << 4) | (l & 15);
  int c = (kk << 5) + fragK(l, e);
  uint32_t i = (uint32_t)(b * 512 + c);
  uint32_t o0, o1;
  threefry(kf[0], kf[1], 0u, i, &o0, &o1);
  Apack[(size_t)sl * 131072 + tb] = f2bf(bits2normal(o0 ^ o1));
}

// S = tanh(noise @ Ws^T + b_s). Writes split pre-permuted layouts:
//   Snz (n>=256): [step][Wg][tid(=row*32+h/8)][8]   (phase-B thread order)
//   Sny (n<256):  [step][Wg][tid(=wv*64+l)][8]      (phase-C lane order, e=(tz_<<2)|r)
__global__ __launch_bounds__(512) void k_sgemm(const u16* __restrict__ Apack,
                                               const u16* __restrict__ Wspack,
                                               const float* __restrict__ b_s,
                                               u16* __restrict__ Sny, u16* __restrict__ Snz) {
  int sl = blockIdx.x; int nq = blockIdx.y;
  int l = threadIdx.x & 63; int wv = threadIdx.x >> 6;
  const u16* Ab = Apack + (size_t)sl * 131072;
#pragma unroll 1
  for (int mtl = 0; mtl < 2; ++mtl) {
    int mt = 2 * wv + mtl;
    bf16x8_t af[16];
#pragma unroll
    for (int kk = 0; kk < 16; ++kk)
      af[kk] = *reinterpret_cast<const bf16x8_t*>(Ab + ((size_t)(mt * 16 + kk) * 64 + l) * 8);
#pragma unroll 1
    for (int ntl = 0; ntl < 8; ++ntl) {
      int nt = nq * 8 + ntl;
      f32x4_t acc = {0.f, 0.f, 0.f, 0.f};
#pragma unroll
      for (int kk = 0; kk < 16; ++kk) {
        bf16x8_t bfr = *reinterpret_cast<const bf16x8_t*>(Wspack + ((size_t)(nt * 16 + kk) * 64 + l) * 8);
        acc = mfma16(af[kk], bfr, acc);
      }
      int n = (nt << 4) | (l & 15);
      float bs = b_s[n];
#pragma unroll
      for (int r = 0; r < 4; ++r) {
        int m = (mt << 4) + ((l >> 4) << 2) + r;
        u16 v = f2bf(tanh_f(acc[r] + bs));
        int Wg = m >> 4, row = m & 15;
        if (n >= 256) {
          int h = n - 256;
          Snz[(((size_t)sl * 16 + Wg) * 512 + ((row << 5) | (h >> 3))) * 8 + (h & 7)] = v;
        } else {
          int tz = n >> 4;
          int e = ((tz & 1) << 2) | (row & 3);
          int ll = ((row >> 2) << 4) | (n & 15);
          Sny[(((size_t)sl * 16 + Wg) * 512 + ((tz >> 1) * 64 + ll)) * 8 + e] = v;
        }
      }
    }
  }
}

// ---------------------------------------------------------------------------
__global__ __launch_bounds__(512, 1) void k_recur(
    const float* __restrict__ dt,
    const u16* __restrict__ Epack, const u16* __restrict__ Wipack, const u16* __restrict__ Wzpack,
    const float* __restrict__ biasD0, const float* __restrict__ biasDn,
    const float* __restrict__ b_z, const float* __restrict__ W_dt, const float* __restrict__ b_dt,
    const u16* __restrict__ inpPack, const u16* __restrict__ Sny, const u16* __restrict__ Snz,
    u16* __restrict__ Ypack, float* __restrict__ ystate, float* __restrict__ zstate,
    int t0, int Tcc)
{
  extern __shared__ char lds_raw[];
  float* G   = (float*)lds_raw;               // [16][1028] fp32          (65792 B)
  u16* ypre  = (u16*)(lds_raw + 65792);       // 4096 u16, swizzled granules
  u16* ypost = ypre + 4096;
  u16* zbf   = ypost + 4096;
  float* sc  = (float*)(zbf + 4096);          // 48 floats
  u16* thW   = (u16*)(lds_raw + 90624);       // [8][4096] u16 = 64KB, th j=2 tiles

  const int Wg = blockIdx.x;
  const int tid = threadIdx.x;
  const int l = tid & 63;
  const int wv = tid >> 6;
  const int row = tid >> 5;                   // phase-B row 0..15
  const int k0 = (tid & 31) * 8;              // phase-B col base

  // ---- persistent registers ----
  float zc[8];                                // z carry (row, k0+j)
  float yc[2][4];                             // y carry (tz_, r)
  float biasA0[8], biasAn[8], bzl[2];
  bf16x8_t wzf[2][8];                         // Wz weights, register-resident
  bf16x8_t hp0[8], hp1[8];                    // th weights j=0,1, register-resident

  // ---- stage th j=2 tiles into LDS (toh = 80+wv) ----
  for (int i = tid; i < 4096; i += 512) {
    int w = i >> 9; int o = (i & 511) << 3;
    *reinterpret_cast<uint4*>(thW + w * 4096 + o) =
        *reinterpret_cast<const uint4*>(Epack + (size_t)(80 + w) * 4096 + o);
  }
  // ---- register-cache Wz and th j=0,1 ----
#pragma unroll
  for (int tz_ = 0; tz_ < 2; ++tz_)
#pragma unroll
    for (int kk = 0; kk < 8; ++kk)
      wzf[tz_][kk] = *reinterpret_cast<const bf16x8_t*>(
          Wzpack + (size_t)(2 * wv + tz_) * 4096 + (size_t)kk * 512 + (size_t)l * 8);
#pragma unroll
  for (int kk = 0; kk < 8; ++kk) {
    hp0[kk] = *reinterpret_cast<const bf16x8_t*>(
        Epack + (size_t)(64 + wv) * 4096 + (size_t)kk * 512 + (size_t)l * 8);
    hp1[kk] = *reinterpret_cast<const bf16x8_t*>(
        Epack + (size_t)(72 + wv) * 4096 + (size_t)kk * 512 + (size_t)l * 8);
  }

  // init
  {
#pragma unroll
    for (int j = 0; j < 8; ++j) {
      int to = wv + 8 * j;
      int n = (to << 4) | (l & 15);
      biasA0[j] = biasD0[n];
      biasAn[j] = biasDn[n];
    }
#pragma unroll
    for (int tz_ = 0; tz_ < 2; ++tz_) bzl[tz_] = b_z[((2 * wv + tz_) << 4) | (l & 15)];
    if (t0 == 0) {
#pragma unroll
      for (int j = 0; j < 8; ++j) zc[j] = 0.f;
#pragma unroll
      for (int tz_ = 0; tz_ < 2; ++tz_)
#pragma unroll
        for (int r = 0; r < 4; ++r) yc[tz_][r] = 0.f;
#pragma unroll
      for (int j = 0; j < 8; ++j) {
        int k = k0 + j;
        int ls = (((k & 15) >> 2) << 4) | row;
        int e = (k & 3) | (((k >> 4) & 1) << 2);
        ypost[(k >> 5) * 512 + gsw(ls) * 8 + e] = 0;
      }
    } else {
#pragma unroll
      for (int j = 0; j < 8; ++j) zc[j] = zstate[(size_t)(Wg * 16 + row) * 256 + k0 + j];
#pragma unroll
      for (int tz_ = 0; tz_ < 2; ++tz_) {
        int n = ((2 * wv + tz_) << 4) | (l & 15);
#pragma unroll
        for (int r = 0; r < 4; ++r)
          yc[tz_][r] = ystate[(size_t)(Wg * 16 + 4 * (l >> 4) + r) * 256 + n];
      }
#pragma unroll
      for (int j = 0; j < 8; ++j) {
        int k = k0 + j;
        float yv = ystate[(size_t)(Wg * 16 + row) * 256 + k];
        int ls = (((k & 15) >> 2) << 4) | row;
        int e = (k & 3) | (((k >> 4) & 1) << 2);
        ypost[(k >> 5) * 512 + gsw(ls) * 8 + e] = f2bf(yv);
      }
    }
  }
  __syncthreads();

  float wdt0 = W_dt[0], wdt1 = W_dt[1], bdt0 = b_dt[0], bdt1 = b_dt[1];

  for (int tl = 0; tl < Tcc; ++tl) {
    int t = t0 + tl;
    if (tid < 16) {
      float dl = dt[(size_t)t * 256 + Wg * 16 + tid] / 10.0f;
      sc[tid] = dl;
      sc[16 + tid] = sigm(fmaf(dl, wdt0, bdt0));   // -> ms_dt_bar (y gate)
      sc[32 + tid] = sigm(fmaf(dl, wdt1, bdt1));   // -> ms_dt (z gate)
    }
    for (int d = 0; d < 10; ++d) {
      int step = tl * 10 + d;
      // ---- prefetch noise (consumed in B and C) ----
      uint4 snz = *reinterpret_cast<const uint4*>(Snz + (((size_t)step * 16 + Wg) * 512 + tid) * 8);
      uint4 sny = *reinterpret_cast<const uint4*>(Sny + (((size_t)step * 16 + Wg) * 512 + tid) * 8);

      // ---- Phase A: merged ti + th, acc-fused ----
      {
        bf16x8_t a1[8], ag[8];
        if (d == 0) {
          const u16* ap = inpPack + (size_t)(tl * 16 + Wg) * 4096 + (size_t)l * 8;
#pragma unroll
          for (int kk = 0; kk < 8; ++kk) a1[kk] = *reinterpret_cast<const bf16x8_t*>(ap + kk * 512);
        } else {
#pragma unroll
          for (int kk = 0; kk < 8; ++kk)
            a1[kk] = *reinterpret_cast<const bf16x8_t*>(ypre + kk * 512 + gsw(l) * 8);
        }
#pragma unroll
        for (int kk = 0; kk < 8; ++kk)
          ag[kk] = *reinterpret_cast<const bf16x8_t*>(ypost + kk * 512 + gsw(l) * 8);
        const u16* BW = (d == 0) ? Wipack : Epack;
#pragma unroll
        for (int j = 0; j < 8; ++j) {
          int to = wv + 8 * j;
          const u16* bp = BW + (size_t)to * 4096 + (size_t)l * 8;
          f32x4_t acc = {0.f, 0.f, 0.f, 0.f};
#pragma unroll
          for (int kk = 0; kk < 8; ++kk)
            acc = mfma16(a1[kk], *reinterpret_cast<const bf16x8_t*>(bp + kk * 512), acc);
          if (j <= 3 || j >= 6) {
#pragma unroll
            for (int kk = 0; kk < 8; ++kk) {
              bf16x8_t h;
              if (j == 0) h = hp0[kk];
              else if (j == 1) h = hp1[kk];
              else if (j == 2) h = *reinterpret_cast<const bf16x8_t*>(thW + wv * 4096 + kk * 512 + l * 8);
              else {
                int toh = (j == 3) ? (88 + wv) : (48 + to);
                h = *reinterpret_cast<const bf16x8_t*>(
                    Epack + (size_t)toh * 4096 + (size_t)kk * 512 + (size_t)l * 8);
              }
              acc = mfma16(ag[kk], h, acc);
            }
          }
          float bv = (d == 0) ? biasA0[j] : biasAn[j];
          int n = (to << 4) | (l & 15);
#pragma unroll
          for (int r = 0; r < 4; ++r)
            G[(4 * (l >> 4) + r) * 1028 + n] = acc[r] + bv;
        }
      }
      __syncthreads();

      // ---- Phase B: z update (carry in regs), write zbf frags ----
      {
        float dl = sc[row], s2v = sc[32 + row];
        f32x4_t p2a = *(const f32x4_t*)&G[row * 1028 + 256 + k0];
        f32x4_t p2b = *(const f32x4_t*)&G[row * 1028 + 256 + k0 + 4];
        f32x4_t iya = *(const f32x4_t*)&G[row * 1028 + 768 + k0];
        f32x4_t iyb = *(const f32x4_t*)&G[row * 1028 + 768 + k0 + 4];
        const u16* nzp = (const u16*)&snz;
        union { u16 h[4]; uint2 v; } zlo, zhi;
#pragma unroll
        for (int j = 0; j < 4; ++j) {
          float ms = s2v * sigm(p2a[j]);
          float zn = (1.0f - ms) * zc[j] + ms * tanh_f(iya[j]);
          zlo.h[j] = f2bf(zn);
          zc[j] = fmaf(bf2f(nzp[j]), dl, zn);
        }
#pragma unroll
        for (int j = 0; j < 4; ++j) {
          float ms = s2v * sigm(p2b[j]);
          float zn = (1.0f - ms) * zc[4 + j] + ms * tanh_f(iyb[j]);
          zhi.h[j] = f2bf(zn);
          zc[4 + j] = fmaf(bf2f(nzp[4 + j]), dl, zn);
        }
        int kk = k0 >> 5;
        int e0 = ((k0 >> 4) & 1) << 2;
        int ls0 = (((k0) & 15) >> 2 << 4) | row;
        int ls1 = (((k0 + 4) & 15) >> 2 << 4) | row;
        *reinterpret_cast<uint2*>(&zbf[kk * 512 + gsw(ls0) * 8 + e0]) = zlo.v;
        *reinterpret_cast<uint2*>(&zbf[kk * 512 + gsw(ls1) * 8 + e0]) = zhi.v;
      }
      __syncthreads();

      // ---- Phase C: W_z MFMA (register weights) + y update ----
      {
        bf16x8_t zfr[8];
#pragma unroll
        for (int kk = 0; kk < 8; ++kk)
          zfr[kk] = *reinterpret_cast<const bf16x8_t*>(zbf + kk * 512 + gsw(l) * 8);
        f32x4_t uacc[2];
#pragma unroll
        for (int tz_ = 0; tz_ < 2; ++tz_) {
          f32x4_t acc = {0.f, 0.f, 0.f, 0.f};
#pragma unroll
          for (int kk = 0; kk < 8; ++kk) acc = mfma16(zfr[kk], wzf[tz_][kk], acc);
          uacc[tz_] = acc;
        }
        const u16* nyp = (const u16*)&sny;
#pragma unroll
        for (int tz_ = 0; tz_ < 2; ++tz_) {
          int n = ((2 * wv + tz_) << 4) | (l & 15);
#pragma unroll
          for (int r = 0; r < 4; ++r) {
            int m2 = 4 * (l >> 4) + r;
            float u = uacc[tz_][r] + bzl[tz_] + G[m2 * 1028 + 512 + n];
            float msb = sc[16 + m2] * sigm(G[m2 * 1028 + n]);
            float yn = (1.0f - msb) * yc[tz_][r] + msb * tanh_f(u);
            float ypn = fmaf(bf2f(nyp[(tz_ << 2) | r]), sc[m2], yn);
            yc[tz_][r] = ypn;
            int kky = n >> 5;
            int lsy = (((n & 15) >> 2) << 4) | m2;
            int ey = (n & 3) | (((n >> 4) & 1) << 2);
            int off = kky * 512 + gsw(lsy) * 8 + ey;
            ypre[off] = f2bf(yn);
            ypost[off] = f2bf(ypn);
            if (d == 9)
              Ypack[(size_t)(tl * 16 + Wg) * 4096 + kky * 512 + lsy * 8 + ey] = f2bf(ypn);
          }
        }
      }
      __syncthreads();
    }
  }
  // ---- store carries ----
#pragma unroll
  for (int j = 0; j < 8; ++j) zstate[(size_t)(Wg * 16 + row) * 256 + k0 + j] = zc[j];
#pragma unroll
  for (int tz_ = 0; tz_ < 2; ++tz_) {
    int n = ((2 * wv + tz_) << 4) | (l & 15);
#pragma unroll
    for (int r = 0; r < 4; ++r)
      ystate[(size_t)(Wg * 16 + 4 * (l >> 4) + r) * 256 + n] = yc[tz_][r];
  }
}

// out[t] = Y[t] @ W_c^T + b_c
__global__ __launch_bounds__(512) void k_out(const u16* __restrict__ Ypack, const u16* __restrict__ Wcpack,
                                             const float* __restrict__ b_c, float* __restrict__ out, int t0) {
  int tl = blockIdx.x; int mh = blockIdx.y;
  int l = threadIdx.x & 63; int wv = threadIdx.x >> 6;
  int mt = mh * 8 + wv;
  const u16* Ab = Ypack + (size_t)(tl * 16 + mt) * 4096 + (size_t)l * 8;
  bf16x8_t af[8];
#pragma unroll
  for (int kk = 0; kk < 8; ++kk) af[kk] = *reinterpret_cast<const bf16x8_t*>(Ab + kk * 512);
#pragma unroll 1
  for (int nt = 0; nt < 16; ++nt) {
    f32x4_t acc = {0.f, 0.f, 0.f, 0.f};
    const u16* bp = Wcpack + ((size_t)nt * 8 * 64 + l) * 8;
#pragma unroll
    for (int kk = 0; kk < 8; ++kk) {
      bf16x8_t bfr = *reinterpret_cast<const bf16x8_t*>(bp + kk * 512);
      acc = mfma16(af[kk], bfr, acc);
    }
    int n = (nt << 4) | (l & 15);
    float bc = b_c[n];
#pragma unroll
    for (int r = 0; r < 4; ++r) {
      int m = (mt << 4) + ((l >> 4) << 2) + r;
      out[((size_t)(t0 + tl) * 256 + m) * 256 + n] = acc[r] + bc;
    }
  }
}

// ---------------------------------------------------------------------------
extern "C" void kernel_launch(void* const* d_in, const int* in_sizes, int n_in,
                              void* d_out, int out_size, void* d_ws, size_t ws_size,
                              hipStream_t stream) {
  const float* input = (const float*)d_in[0];
  const float* dt    = (const float*)d_in[1];
  const float* W_i   = (const float*)d_in[2];
  const float* b_i   = (const float*)d_in[3];
  const float* W_h   = (const float*)d_in[4];
  const float* b_h   = (const float*)d_in[5];
  const float* W_z   = (const float*)d_in[6];
  const float* b_z   = (const float*)d_in[7];
  const float* W_dt  = (const float*)d_in[8];
  const float* b_dt  = (const float*)d_in[9];
  const float* W_c   = (const float*)d_in[10];
  const float* b_c   = (const float*)d_in[11];
  const float* W_s   = (const float*)d_in[12];
  const float* b_s   = (const float*)d_in[13];
  float* out = (float*)d_out;

  char* ws = (char*)d_ws;
  size_t off = 0;
  auto alloc = [&](size_t bytes) -> char* {
    char* p = ws + off; off = (off + bytes + 255) & ~(size_t)255; return p;
  };
  u16* Epack   = (u16*)alloc((size_t)112 * 8 * 512 * 2);   // [Wic;Wh] 1792x256
  u16* Wipack  = (u16*)alloc((size_t)64 * 8 * 512 * 2);
  u16* Wzpack  = (u16*)alloc((size_t)16 * 8 * 512 * 2);
  u16* Wcpack  = (u16*)alloc((size_t)16 * 8 * 512 * 2);
  u16* Wspack  = (u16*)alloc((size_t)32 * 16 * 512 * 2);
  float* bip   = (float*)alloc(1024 * 4);
  float* biasD0= (float*)alloc(1024 * 4);
  float* biasDn= (float*)alloc(1024 * 4);
  float* Wic   = (float*)alloc((size_t)1024 * 256 * 4);
  float* ystate= (float*)alloc((size_t)256 * 256 * 4);
  float* zstate= (float*)alloc((size_t)256 * 256 * 4);
  size_t fixed = off;
  size_t per_t = (size_t)10 * 131072 * 2      // Apack
               + (size_t)10 * 65536 * 2 * 2   // Sny + Snz
               + (size_t)16 * 8 * 512 * 2 + (size_t)16 * 8 * 512 * 2  // inpPack + Ypack
               + 4 * 256;
  int Tc = 1;
  if (ws_size > fixed + per_t) {
    size_t n = (ws_size - fixed) / per_t;
    Tc = (n > 128) ? 128 : (int)n;
  }
  if (Tc < 1) Tc = 1;
  u16* Apack   = (u16*)alloc((size_t)Tc * 10 * 131072 * 2);
  u16* Sny     = (u16*)alloc((size_t)Tc * 10 * 65536 * 2);
  u16* Snz     = (u16*)alloc((size_t)Tc * 10 * 65536 * 2);
  u16* inpPack = (u16*)alloc((size_t)Tc * 16 * 8 * 512 * 2);
  u16* Ypack   = (u16*)alloc((size_t)Tc * 16 * 8 * 512 * 2);

  hipFuncSetAttribute((const void*)k_recur, hipFuncAttributeMaxDynamicSharedMemorySize, R_LDS_BYTES);

  k_prep<<<1024, 256, 0, stream>>>(W_i, W_c, b_i, b_c, Wic, bip);
  k_bias<<<4, 256, 0, stream>>>(b_i, bip, b_h, biasD0, biasDn);
  k_packw<<<(112 * 8 * 64) / 256, 256, 0, stream>>>(Wic, 1024, W_h, Epack, 1792, 256);
  k_packw<<<(64 * 8 * 64) / 256, 256, 0, stream>>>(W_i, 1024, (const float*)nullptr, Wipack, 1024, 256);
  k_packw<<<(16 * 8 * 64) / 256, 256, 0, stream>>>(W_z, 256, (const float*)nullptr, Wzpack, 256, 256);
  k_packw<<<(16 * 8 * 64) / 256, 256, 0, stream>>>(W_c, 256, (const float*)nullptr, Wcpack, 256, 256);
  k_packw<<<(32 * 16 * 64) / 256, 256, 0, stream>>>(W_s, 512, (const float*)nullptr, Wspack, 512, 512);

  for (int t0 = 0; t0 < 128; t0 += Tc) {
    int Tcc = (128 - t0 < Tc) ? (128 - t0) : Tc;
    int nsteps = Tcc * 10;
    k_gen<<<nsteps * 128, 1024, 0, stream>>>(Apack, t0 * 10);
    dim3 g2(nsteps, 4);
    k_sgemm<<<g2, 512, 0, stream>>>(Apack, Wspack, b_s, Sny, Snz);
    int totalA = Tcc * 16 * 8 * 64;
    k_packa<<<(totalA + 255) / 256, 256, 0, stream>>>(input, t0, Tcc, inpPack);
    k_recur<<<16, 512, R_LDS_BYTES, stream>>>(dt, Epack, Wipack, Wzpack, biasD0, biasDn,
                                              b_z, W_dt, b_dt, inpPack, Sny, Snz,
                                              Ypack, ystate, zstate, t0, Tcc);
    dim3 ge(Tcc, 2);
    k_out<<<ge, 512, 0, stream>>>(Ypack, Wcpack, b_c, out, t0);
  }
}

// Round 5
// 16127.792 us; speedup vs baseline: 1.5045x; 1.5045x over previous
//
#include <hip/hip_runtime.h>
#include <stdint.h>

// ---------------------------------------------------------------------------
// LEM-style noisy RNN. T=128 x DIV=10 sequential steps, B=256, H=256.
// k_recur: 64 WGs = 16 batch-groups x 4 roles (Y0,Y1,Z0,Z1), N-split so each
// WG streams only 256KB of weights per step (was 1MB). Cross-WG y/z fragment
// exchange via L2 buffers + agent-scope atomic flags (double-buffered,
// monotone per-dispatch counters; all 4 roles of a group on one XCD).
//   Z(hz): A computes G cols 256+hz*128..(+128) [pre2] and 768+hz*128.. [iy],
//          B updates z half, publishes z frags.
//   Y(hy): A computes G cols hy*128.. [dt1] and 512+hy*128.. [i_z],
//          C does W_z MFMA (half), y update, publishes y frags.
// ---------------------------------------------------------------------------

typedef __attribute__((ext_vector_type(8))) short bf16x8_t;
typedef __attribute__((ext_vector_type(4))) float f32x4_t;
typedef unsigned short u16;

__device__ __forceinline__ float bf2f(u16 b) {
  union { uint32_t u; float f; } v; v.u = ((uint32_t)b) << 16; return v.f;
}
__device__ __forceinline__ u16 f2bf(float f) {
  union { float f; uint32_t u; } v; v.f = f;
  uint32_t x = v.u;
  return (u16)((x + 0x7FFFu + ((x >> 16) & 1u)) >> 16);   // RNE
}
__device__ __forceinline__ f32x4_t mfma16(bf16x8_t a, bf16x8_t b, f32x4_t c) {
  return __builtin_amdgcn_mfma_f32_16x16x32_bf16(a, b, c, 0, 0, 0);
}
__device__ __forceinline__ float sigm(float x) { return 1.0f / (1.0f + __expf(-x)); }
__device__ __forceinline__ float tanh_f(float x) {
  float t = __expf(-2.0f * fabsf(x));
  float r = (1.0f - t) / (1.0f + t);
  return x < 0.0f ? -r : r;
}

// MFMA 16x16x32 bf16 A-frag K-position for lane l, elem e
__device__ __forceinline__ int fragK(int l, int e) {
  return ((l >> 4) << 2) + (e & 3) + ((e >> 2) << 4);
}

// ---- JAX threefry2x32 (20 rounds) ----
__device__ __forceinline__ void threefry(uint32_t k0, uint32_t k1, uint32_t x0, uint32_t x1,
                                         uint32_t* o0, uint32_t* o1) {
  uint32_t ks2 = k0 ^ k1 ^ 0x1BD11BDAu;
  x0 += k0; x1 += k1;
#define TFR(rot) { x0 += x1; x1 = (x1 << rot) | (x1 >> (32 - rot)); x1 ^= x0; }
  TFR(13) TFR(15) TFR(26) TFR(6)   x0 += k1;  x1 += ks2 + 1u;
  TFR(17) TFR(29) TFR(16) TFR(24)  x0 += ks2; x1 += k0 + 2u;
  TFR(13) TFR(15) TFR(26) TFR(6)   x0 += k0;  x1 += k1 + 3u;
  TFR(17) TFR(29) TFR(16) TFR(24)  x0 += k1;  x1 += ks2 + 4u;
  TFR(13) TFR(15) TFR(26) TFR(6)   x0 += ks2; x1 += k0 + 5u;
#undef TFR
  *o0 = x0; *o1 = x1;
}

// bits -> N(0,1), matches jax.random.normal f32 (XLA erfinv poly)
__device__ __forceinline__ float bits2normal(uint32_t bits) {
  union { uint32_t u; float f; } cv; cv.u = 0x3F800000u | (bits >> 9);
  float f = cv.f - 1.0f;
  float u = fmaf(f, 2.0f, -0.99999994f);
  u = fmaxf(u, -0.99999994f);
  float w = -log1pf(-u * u);
  float p;
  if (w < 5.0f) {
    w = w - 2.5f;
    p = 2.81022636e-08f;
    p = fmaf(p, w, 3.43273939e-07f);
    p = fmaf(p, w, -3.5233877e-06f);
    p = fmaf(p, w, -4.39150654e-06f);
    p = fmaf(p, w, 0.00021858087f);
    p = fmaf(p, w, -0.00125372503f);
    p = fmaf(p, w, -0.00417768164f);
    p = fmaf(p, w, 0.246640727f);
    p = fmaf(p, w, 1.50140941f);
  } else {
    w = sqrtf(w) - 3.0f;
    p = -0.000200214257f;
    p = fmaf(p, w, 0.000100950558f);
    p = fmaf(p, w, 0.00134934322f);
    p = fmaf(p, w, -0.00367342844f);
    p = fmaf(p, w, 0.00573950773f);
    p = fmaf(p, w, -0.0076224613f);
    p = fmaf(p, w, 0.00943887047f);
    p = fmaf(p, w, 1.00167406f);
    p = fmaf(p, w, 2.83297682f);
  }
  return 1.41421354f * p * u;
}

// ---------------------------------------------------------------------------
__global__ void k_prep(const float* __restrict__ W_i, const float* __restrict__ W_c,
                       const float* __restrict__ b_i, const float* __restrict__ b_c,
                       float* __restrict__ Wic, float* __restrict__ bip) {
  __shared__ float wi[256];
  __shared__ float red[256];
  int o = blockIdx.x; int tid = threadIdx.x;
  wi[tid] = W_i[o * 256 + tid];
  __syncthreads();
  float acc = 0.f;
  for (int j = 0; j < 256; ++j) acc = fmaf(wi[j], W_c[j * 256 + tid], acc);
  Wic[(size_t)o * 256 + tid] = acc;
  red[tid] = wi[tid] * b_c[tid];
  __syncthreads();
  for (int s = 128; s > 0; s >>= 1) { if (tid < s) red[tid] += red[tid + s]; __syncthreads(); }
  if (tid == 0) bip[o] = b_i[o] + red[0];
}

__global__ void k_bias(const float* __restrict__ b_i, const float* __restrict__ bip,
                       const float* __restrict__ b_h,
                       float* __restrict__ biasD0, float* __restrict__ biasDn) {
  int c = blockIdx.x * 256 + threadIdx.x;
  float bh = (c < 512) ? b_h[c] : (c >= 768 ? b_h[c - 256] : 0.f);
  biasD0[c] = b_i[c] + bh;
  biasDn[c] = bip[c] + bh;
}

__global__ void k_packw(const float* __restrict__ srcA, int rowsA, const float* __restrict__ srcB,
                        u16* __restrict__ dst, int O, int K) {
  int t = blockIdx.x * blockDim.x + threadIdx.x;
  int KK = K >> 5;
  int total = (O >> 4) * KK * 64;
  if (t >= total) return;
  int l = t & 63; int kk = (t >> 6) % KK; int to = t / (64 * KK);
  int n = (to << 4) | (l & 15);
  int kb = (kk << 5) + ((l >> 4) << 2);
  const float* src = (n < rowsA) ? (srcA + (size_t)n * K) : (srcB + (size_t)(n - rowsA) * K);
  u16 out[8];
#pragma unroll
  for (int e = 0; e < 8; ++e) out[e] = f2bf(src[kb + (e & 3) + ((e >> 2) << 4)]);
  *reinterpret_cast<uint4*>(dst + (size_t)t * 8) = *reinterpret_cast<const uint4*>(out);
}

__global__ void k_packa(const float* __restrict__ inp, int t0, int Tcc, u16* __restrict__ dst) {
  int t = blockIdx.x * blockDim.x + threadIdx.x;
  int total = Tcc * 16 * 8 * 64;
  if (t >= total) return;
  int l = t & 63; int kk = (t >> 6) & 7; int mt = (t >> 9) & 15; int tl = t >> 13;
  int b = (mt << 4) | (l & 15);
  int kb = (kk << 5) + ((l >> 4) << 2);
  const float* src = inp + ((size_t)(t0 + tl) * 256 + b) * 256;
  u16 out[8];
#pragma unroll
  for (int e = 0; e < 8; ++e) out[e] = f2bf(src[kb + (e & 3) + ((e >> 2) << 4)]);
  *reinterpret_cast<uint4*>(dst + (size_t)t * 8) = *reinterpret_cast<const uint4*>(out);
}

// noise gen, JAX threefry partitionable: bits[i] = o0^o1, (o0,o1)=threefry(key, 0, i)
__global__ void k_gen(u16* __restrict__ Apack, int gstep0) {
  int sl = blockIdx.x >> 7;
  int tb = (blockIdx.x & 127) * 1024 + threadIdx.x;   // [0, 131072)
  __shared__ uint32_t kf[2];
  if (threadIdx.x == 0) {
    uint32_t o0, o1;
    threefry(0u, 1234u, 0u, (uint32_t)(gstep0 + sl), &o0, &o1);
    kf[0] = o0; kf[1] = o1;
  }
  __syncthreads();
  int e = tb & 7; int l = (tb >> 3) & 63; int kk = (tb >> 9) & 15; int mt = tb >> 13;
  int b = (mt << 4) | (l & 15);
  int c = (kk << 5) + fragK(l, e);
  uint32_t i = (uint32_t)(b * 512 + c);
  uint32_t o0, o1;
  threefry(kf[0], kf[1], 0u, i, &o0, &o1);
  Apack[(size_t)sl * 131072 + tb] = f2bf(bits2normal(o0 ^ o1));
}

// S = tanh(noise @ Ws^T + b_s), scattered into per-consumer split layouts:
//   Snz[((sl*16+g)*2+hz)*2048 + tid*4 + slot]  (Z-phase-B thread order)
//   Sny[((sl*16+g)*2+hy)*2048 + tid*4 + r]     (Y-phase-C lane order)
__global__ __launch_bounds__(512) void k_sgemm(const u16* __restrict__ Apack,
                                               const u16* __restrict__ Wspack,
                                               const float* __restrict__ b_s,
                                               u16* __restrict__ Sny, u16* __restrict__ Snz) {
  int sl = blockIdx.x; int nq = blockIdx.y;
  int l = threadIdx.x & 63; int wv = threadIdx.x >> 6;
  const u16* Ab = Apack + (size_t)sl * 131072;
#pragma unroll 1
  for (int mtl = 0; mtl < 2; ++mtl) {
    int mt = 2 * wv + mtl;
    bf16x8_t af[16];
#pragma unroll
    for (int kk = 0; kk < 16; ++kk)
      af[kk] = *reinterpret_cast<const bf16x8_t*>(Ab + ((size_t)(mt * 16 + kk) * 64 + l) * 8);
#pragma unroll 1
    for (int ntl = 0; ntl < 8; ++ntl) {
      int nt = nq * 8 + ntl;
      f32x4_t acc = {0.f, 0.f, 0.f, 0.f};
#pragma unroll
      for (int kk = 0; kk < 16; ++kk) {
        bf16x8_t bfr = *reinterpret_cast<const bf16x8_t*>(Wspack + ((size_t)(nt * 16 + kk) * 64 + l) * 8);
        acc = mfma16(af[kk], bfr, acc);
      }
      int n = (nt << 4) | (l & 15);
      float bs = b_s[n];
#pragma unroll
      for (int r = 0; r < 4; ++r) {
        int m = (mt << 4) + ((l >> 4) << 2) + r;
        u16 v = f2bf(tanh_f(acc[r] + bs));
        int g = m >> 4, row = m & 15;
        if (n >= 256) {
          int h = n - 256; int hz = h >> 7; int h2 = h & 127;
          Snz[((((size_t)sl * 16 + g) * 2 + hz) * 512 + ((row << 5) | (h2 >> 2))) * 4 + (h2 & 3)] = v;
        } else {
          int hy = n >> 7; int wv2 = (n >> 4) & 7;
          int l2 = ((row >> 2) << 4) | (n & 15);
          Sny[((((size_t)sl * 16 + g) * 2 + hy) * 512 + (wv2 * 64 + l2)) * 4 + (row & 3)] = v;
        }
      }
    }
  }
}

// ---------------------------------------------------------------------------
// Recurrence, 64 WGs. wgid = role*16 + g  (all roles of g land on XCD g%8).
// role 0/1 = Y(hy=0/1), role 2/3 = Z(hz=0/1).
__global__ __launch_bounds__(512) void k_recur(
    const float* __restrict__ dt,
    const u16* __restrict__ Epack, const u16* __restrict__ Wipack, const u16* __restrict__ Wzpack,
    const float* __restrict__ biasD0, const float* __restrict__ biasDn,
    const float* __restrict__ b_z, const float* __restrict__ W_dt, const float* __restrict__ b_dt,
    const u16* __restrict__ inpPack, const u16* __restrict__ Sny, const u16* __restrict__ Snz,
    u16* __restrict__ Ypack, float* __restrict__ ystate, float* __restrict__ zstate,
    u16* __restrict__ yexch, u16* __restrict__ zexch, int* __restrict__ flags,
    int t0, int Tcc)
{
  __shared__ float G[16 * 264];      // [16 rows][2 panels x 132]
  __shared__ u16 a1b[4096];          // A-operand frags (x or y_pre)
  __shared__ u16 agb[4096];          // y_post frags
  __shared__ u16 zb[4096];           // z frags (Y only)
  __shared__ float sc[48];

  const int wgid = blockIdx.x;
  const int g = wgid & 15;
  const int role = wgid >> 4;
  const bool isY = role < 2;
  const int half = role & 1;
  const int tid = threadIdx.x;
  const int l = tid & 63;
  const int wv = tid >> 6;
  const int row = tid >> 5;
  const int hq = (tid & 31) * 4;     // local col base for B / init packing

  int* flg = flags + g * 16;
  const int nsteps = Tcc * 10;

  float zc[4];                       // Z carry
  float yc[4];                       // Y carry
  float bias0[2], biasn[2], bzr = 0.f;

  // weight tile indices for this wave
  int tiA0, tiTh0, tiA1, tiTh1 = -1;
  if (isY) {
    tiA0 = half * 8 + wv;        tiTh0 = 64 + half * 8 + wv;   // dt1 (+h_dt1)
    tiA1 = 32 + half * 8 + wv;                                  // i_z
  } else {
    tiA0 = 16 + half * 8 + wv;   tiTh0 = 80 + half * 8 + wv;   // dt2 (+h_dt2)
    tiA1 = 48 + half * 8 + wv;   tiTh1 = 96 + half * 8 + wv;   // i_y (+h_y)
  }
  {
    int c0, c1;
    if (isY) { c0 = half * 128 + wv * 16 + (l & 15); c1 = 512 + c0; bzr = b_z[c0]; }
    else     { c0 = 256 + half * 128 + wv * 16 + (l & 15); c1 = c0 + 512; }
    bias0[0] = biasD0[c0]; biasn[0] = biasDn[c0];
    bias0[1] = biasD0[c1]; biasn[1] = biasDn[c1];
  }

  // ---- init: carries + Y publishes initial y_post frags (buf 0) ----
  if (isY) {
    int n = half * 128 + wv * 16 + (l & 15);
#pragma unroll
    for (int r = 0; r < 4; ++r)
      yc[r] = (t0 == 0) ? 0.f : ystate[(size_t)(g * 16 + 4 * (l >> 4) + r) * 256 + n];
    int k = half * 128 + hq;
    union { u16 h[4]; uint2 v; } pk;
#pragma unroll
    for (int j = 0; j < 4; ++j)
      pk.h[j] = (t0 == 0) ? (u16)0 : f2bf(ystate[(size_t)(g * 16 + row) * 256 + k + j]);
    int kk = k >> 5, e0 = ((k >> 4) & 1) << 2, ls = (((k & 15) >> 2) << 4) | row;
    *reinterpret_cast<uint2*>(&yexch[(((size_t)0 * 16 + g) * 2 + 1) * 4096 + kk * 512 + ls * 8 + e0]) = pk.v;
    __syncthreads();
    if (tid == 0)
      __hip_atomic_store(&flg[half], 1, __ATOMIC_RELEASE, __HIP_MEMORY_SCOPE_AGENT);
  } else {
    int h = half * 128 + hq;
#pragma unroll
    for (int j = 0; j < 4; ++j)
      zc[j] = (t0 == 0) ? 0.f : zstate[(size_t)(g * 16 + row) * 256 + h + j];
  }

  float wdt0 = W_dt[0], wdt1 = W_dt[1], bdt0 = b_dt[0], bdt1 = b_dt[1];

  for (int s = 0; s < nsteps; ++s) {
    int d = s % 10; int tl = s / 10;
    // noise prefetch (independent of flags)
    uint2 nsv = *reinterpret_cast<const uint2*>(
        (isY ? Sny : Snz) + ((((size_t)s * 16 + g) * 2 + half) * 512 + tid) * 4);
    if (d == 0 && tid < 16) {
      float dl = dt[(size_t)(t0 + tl) * 256 + g * 16 + tid] * 0.1f;
      sc[tid] = dl;
      sc[16 + tid] = sigm(fmaf(dl, wdt0, bdt0));
      sc[32 + tid] = sigm(fmaf(dl, wdt1, bdt1));
    }
    // ---- wait y(s) published (both halves) ----
    if (tid == 0) {
      while (__hip_atomic_load(&flg[0], __ATOMIC_ACQUIRE, __HIP_MEMORY_SCOPE_AGENT) < s + 1)
        __builtin_amdgcn_s_sleep(1);
    } else if (tid == 64) {
      while (__hip_atomic_load(&flg[1], __ATOMIC_ACQUIRE, __HIP_MEMORY_SCOPE_AGENT) < s + 1)
        __builtin_amdgcn_s_sleep(1);
    }
    __syncthreads();
    // ---- copy exchange -> LDS ----
    {
      const u16* psrc = yexch + (((size_t)(s & 1) * 16 + g) * 2 + 1) * 4096;
      *reinterpret_cast<uint4*>(agb + tid * 8) = *reinterpret_cast<const uint4*>(psrc + tid * 8);
      const u16* asrc = (d == 0) ? (inpPack + (size_t)(tl * 16 + g) * 4096)
                                 : (yexch + (((size_t)(s & 1) * 16 + g) * 2 + 0) * 4096);
      *reinterpret_cast<uint4*>(a1b + tid * 8) = *reinterpret_cast<const uint4*>(asrc + tid * 8);
    }
    __syncthreads();

    // ---- Phase A: 2 output tiles per wave ----
    {
      bf16x8_t a1[8], ag[8];
#pragma unroll
      for (int kk = 0; kk < 8; ++kk) {
        a1[kk] = *reinterpret_cast<const bf16x8_t*>(a1b + kk * 512 + l * 8);
        ag[kk] = *reinterpret_cast<const bf16x8_t*>(agb + kk * 512 + l * 8);
      }
      const u16* TI = (d == 0) ? Wipack : Epack;
      int cpr = wv * 16 + (l & 15);
      // jt = 0 (fused th for both roles)
      {
        f32x4_t acc = {0.f, 0.f, 0.f, 0.f};
        const u16* bp = TI + (size_t)tiA0 * 4096 + (size_t)l * 8;
        const u16* hp = Epack + (size_t)tiTh0 * 4096 + (size_t)l * 8;
#pragma unroll
        for (int kk = 0; kk < 8; ++kk)
          acc = mfma16(a1[kk], *reinterpret_cast<const bf16x8_t*>(bp + kk * 512), acc);
#pragma unroll
        for (int kk = 0; kk < 8; ++kk)
          acc = mfma16(ag[kk], *reinterpret_cast<const bf16x8_t*>(hp + kk * 512), acc);
        float bv = (d == 0) ? bias0[0] : biasn[0];
#pragma unroll
        for (int r = 0; r < 4; ++r)
          G[(4 * (l >> 4) + r) * 264 + cpr] = acc[r] + bv;
      }
      // jt = 1 (Z: fused th; Y: ti only)
      {
        f32x4_t acc = {0.f, 0.f, 0.f, 0.f};
        const u16* bp = TI + (size_t)tiA1 * 4096 + (size_t)l * 8;
#pragma unroll
        for (int kk = 0; kk < 8; ++kk)
          acc = mfma16(a1[kk], *reinterpret_cast<const bf16x8_t*>(bp + kk * 512), acc);
        if (!isY) {
          const u16* hp = Epack + (size_t)tiTh1 * 4096 + (size_t)l * 8;
#pragma unroll
          for (int kk = 0; kk < 8; ++kk)
            acc = mfma16(ag[kk], *reinterpret_cast<const bf16x8_t*>(hp + kk * 512), acc);
        }
        float bv = (d == 0) ? bias0[1] : biasn[1];
#pragma unroll
        for (int r = 0; r < 4; ++r)
          G[(4 * (l >> 4) + r) * 264 + 132 + cpr] = acc[r] + bv;
      }
    }
    __syncthreads();

    if (!isY) {
      // ---- Phase B: z update (half), publish z frags ----
      float dl = sc[row], s2 = sc[32 + row];
      f32x4_t p2 = *reinterpret_cast<const f32x4_t*>(&G[row * 264 + hq]);
      f32x4_t iy = *reinterpret_cast<const f32x4_t*>(&G[row * 264 + 132 + hq]);
      const u16* nzp = (const u16*)&nsv;
      union { u16 h[4]; uint2 v; } zp;
#pragma unroll
      for (int j = 0; j < 4; ++j) {
        float ms = s2 * sigm(p2[j]);
        float zn = (1.0f - ms) * zc[j] + ms * tanh_f(iy[j]);
        zp.h[j] = f2bf(zn);
        zc[j] = fmaf(bf2f(nzp[j]), dl, zn);
      }
      int h = half * 128 + hq;
      int kk = h >> 5, e0 = ((h >> 4) & 1) << 2, ls = (((h & 15) >> 2) << 4) | row;
      *reinterpret_cast<uint2*>(&zexch[((size_t)(s & 1) * 16 + g) * 4096 + kk * 512 + ls * 8 + e0]) = zp.v;
      __syncthreads();
      if (tid == 0)
        __hip_atomic_store(&flg[2 + half], s + 1, __ATOMIC_RELEASE, __HIP_MEMORY_SCOPE_AGENT);
    } else {
      // ---- wait z(s), copy to LDS ----
      if (tid == 0) {
        while (__hip_atomic_load(&flg[2], __ATOMIC_ACQUIRE, __HIP_MEMORY_SCOPE_AGENT) < s + 1)
          __builtin_amdgcn_s_sleep(1);
      } else if (tid == 64) {
        while (__hip_atomic_load(&flg[3], __ATOMIC_ACQUIRE, __HIP_MEMORY_SCOPE_AGENT) < s + 1)
          __builtin_amdgcn_s_sleep(1);
      }
      __syncthreads();
      {
        const u16* zsrc = zexch + ((size_t)(s & 1) * 16 + g) * 4096;
        *reinterpret_cast<uint4*>(zb + tid * 8) = *reinterpret_cast<const uint4*>(zsrc + tid * 8);
      }
      __syncthreads();
      // ---- Phase C: W_z MFMA (half) + y update, publish y frags ----
      bf16x8_t zfr[8];
#pragma unroll
      for (int kk = 0; kk < 8; ++kk)
        zfr[kk] = *reinterpret_cast<const bf16x8_t*>(zb + kk * 512 + l * 8);
      const u16* wzp = Wzpack + (size_t)(half * 8 + wv) * 4096 + (size_t)l * 8;
      f32x4_t acc = {0.f, 0.f, 0.f, 0.f};
#pragma unroll
      for (int kk = 0; kk < 8; ++kk)
        acc = mfma16(zfr[kk], *reinterpret_cast<const bf16x8_t*>(wzp + kk * 512), acc);
      int cpr = wv * 16 + (l & 15);
      int n = half * 128 + cpr;
      int kky = n >> 5, ey = (n & 3) | (((n >> 4) & 1) << 2);
      u16* ybpre = yexch + (((size_t)((s + 1) & 1) * 16 + g) * 2 + 0) * 4096;
      u16* ybpost = ybpre + 4096;
      const u16* nyp = (const u16*)&nsv;
#pragma unroll
      for (int r = 0; r < 4; ++r) {
        int m2 = 4 * (l >> 4) + r;
        float u = acc[r] + bzr + G[m2 * 264 + 132 + cpr];
        float msb = sc[16 + m2] * sigm(G[m2 * 264 + cpr]);
        float yn = (1.0f - msb) * yc[r] + msb * tanh_f(u);
        float ypn = fmaf(bf2f(nyp[r]), sc[m2], yn);
        yc[r] = ypn;
        int lsy = (((n & 15) >> 2) << 4) | m2;
        int off = kky * 512 + lsy * 8 + ey;
        ybpre[off] = f2bf(yn);
        ybpost[off] = f2bf(ypn);
        if (d == 9)
          Ypack[(size_t)(tl * 16 + g) * 4096 + off] = f2bf(ypn);
      }
      __syncthreads();
      if (tid == 0)
        __hip_atomic_store(&flg[half], s + 2, __ATOMIC_RELEASE, __HIP_MEMORY_SCOPE_AGENT);
    }
  }

  // ---- store carries ----
  if (isY) {
    int n = half * 128 + wv * 16 + (l & 15);
#pragma unroll
    for (int r = 0; r < 4; ++r)
      ystate[(size_t)(g * 16 + 4 * (l >> 4) + r) * 256 + n] = yc[r];
  } else {
    int h = half * 128 + hq;
#pragma unroll
    for (int j = 0; j < 4; ++j)
      zstate[(size_t)(g * 16 + row) * 256 + h + j] = zc[j];
  }
}

// out[t] = Y[t] @ W_c^T + b_c
__global__ __launch_bounds__(512) void k_out(const u16* __restrict__ Ypack, const u16* __restrict__ Wcpack,
                                             const float* __restrict__ b_c, float* __restrict__ out, int t0) {
  int tl = blockIdx.x; int mh = blockIdx.y;
  int l = threadIdx.x & 63; int wv = threadIdx.x >> 6;
  int mt = mh * 8 + wv;
  const u16* Ab = Ypack + (size_t)(tl * 16 + mt) * 4096 + (size_t)l * 8;
  bf16x8_t af[8];
#pragma unroll
  for (int kk = 0; kk < 8; ++kk) af[kk] = *reinterpret_cast<const bf16x8_t*>(Ab + kk * 512);
#pragma unroll 1
  for (int nt = 0; nt < 16; ++nt) {
    f32x4_t acc = {0.f, 0.f, 0.f, 0.f};
    const u16* bp = Wcpack + ((size_t)nt * 8 * 64 + l) * 8;
#pragma unroll
    for (int kk = 0; kk < 8; ++kk) {
      bf16x8_t bfr = *reinterpret_cast<const bf16x8_t*>(bp + kk * 512);
      acc = mfma16(af[kk], bfr, acc);
    }
    int n = (nt << 4) | (l & 15);
    float bc = b_c[n];
#pragma unroll
    for (int r = 0; r < 4; ++r) {
      int m = (mt << 4) + ((l >> 4) << 2) + r;
      out[((size_t)(t0 + tl) * 256 + m) * 256 + n] = acc[r] + bc;
    }
  }
}

// ---------------------------------------------------------------------------
extern "C" void kernel_launch(void* const* d_in, const int* in_sizes, int n_in,
                              void* d_out, int out_size, void* d_ws, size_t ws_size,
                              hipStream_t stream) {
  const float* input = (const float*)d_in[0];
  const float* dt    = (const float*)d_in[1];
  const float* W_i   = (const float*)d_in[2];
  const float* b_i   = (const float*)d_in[3];
  const float* W_h   = (const float*)d_in[4];
  const float* b_h   = (const float*)d_in[5];
  const float* W_z   = (const float*)d_in[6];
  const float* b_z   = (const float*)d_in[7];
  const float* W_dt  = (const float*)d_in[8];
  const float* b_dt  = (const float*)d_in[9];
  const float* W_c   = (const float*)d_in[10];
  const float* b_c   = (const float*)d_in[11];
  const float* W_s   = (const float*)d_in[12];
  const float* b_s   = (const float*)d_in[13];
  float* out = (float*)d_out;

  char* ws = (char*)d_ws;
  size_t off = 0;
  auto alloc = [&](size_t bytes) -> char* {
    char* p = ws + off; off = (off + bytes + 255) & ~(size_t)255; return p;
  };
  u16* Epack   = (u16*)alloc((size_t)112 * 8 * 512 * 2);   // [Wic;Wh] 1792x256
  u16* Wipack  = (u16*)alloc((size_t)64 * 8 * 512 * 2);
  u16* Wzpack  = (u16*)alloc((size_t)16 * 8 * 512 * 2);
  u16* Wcpack  = (u16*)alloc((size_t)16 * 8 * 512 * 2);
  u16* Wspack  = (u16*)alloc((size_t)32 * 16 * 512 * 2);
  float* bip   = (float*)alloc(1024 * 4);
  float* biasD0= (float*)alloc(1024 * 4);
  float* biasDn= (float*)alloc(1024 * 4);
  float* Wic   = (float*)alloc((size_t)1024 * 256 * 4);
  float* ystate= (float*)alloc((size_t)256 * 256 * 4);
  float* zstate= (float*)alloc((size_t)256 * 256 * 4);
  u16* yexch   = (u16*)alloc((size_t)2 * 16 * 2 * 4096 * 2);
  u16* zexch   = (u16*)alloc((size_t)2 * 16 * 4096 * 2);
  int* flags   = (int*)alloc((size_t)16 * 16 * 4);
  size_t fixed = off;
  size_t per_t = (size_t)10 * 131072 * 2      // Apack
               + (size_t)10 * 65536 * 2 * 2   // Sny + Snz
               + (size_t)16 * 8 * 512 * 2 + (size_t)16 * 8 * 512 * 2  // inpPack + Ypack
               + 4 * 256;
  int Tc = 1;
  if (ws_size > fixed + per_t) {
    size_t n = (ws_size - fixed) / per_t;
    Tc = (n > 128) ? 128 : (int)n;
  }
  if (Tc < 1) Tc = 1;
  u16* Apack   = (u16*)alloc((size_t)Tc * 10 * 131072 * 2);
  u16* Sny     = (u16*)alloc((size_t)Tc * 10 * 65536 * 2);
  u16* Snz     = (u16*)alloc((size_t)Tc * 10 * 65536 * 2);
  u16* inpPack = (u16*)alloc((size_t)Tc * 16 * 8 * 512 * 2);
  u16* Ypack   = (u16*)alloc((size_t)Tc * 16 * 8 * 512 * 2);

  k_prep<<<1024, 256, 0, stream>>>(W_i, W_c, b_i, b_c, Wic, bip);
  k_bias<<<4, 256, 0, stream>>>(b_i, bip, b_h, biasD0, biasDn);
  k_packw<<<(112 * 8 * 64) / 256, 256, 0, stream>>>(Wic, 1024, W_h, Epack, 1792, 256);
  k_packw<<<(64 * 8 * 64) / 256, 256, 0, stream>>>(W_i, 1024, (const float*)nullptr, Wipack, 1024, 256);
  k_packw<<<(16 * 8 * 64) / 256, 256, 0, stream>>>(W_z, 256, (const float*)nullptr, Wzpack, 256, 256);
  k_packw<<<(16 * 8 * 64) / 256, 256, 0, stream>>>(W_c, 256, (const float*)nullptr, Wcpack, 256, 256);
  k_packw<<<(32 * 16 * 64) / 256, 256, 0, stream>>>(W_s, 512, (const float*)nullptr, Wspack, 512, 512);

  for (int t0 = 0; t0 < 128; t0 += Tc) {
    int Tcc = (128 - t0 < Tc) ? (128 - t0) : Tc;
    int nsteps = Tcc * 10;
    k_gen<<<nsteps * 128, 1024, 0, stream>>>(Apack, t0 * 10);
    dim3 g2(nsteps, 4);
    k_sgemm<<<g2, 512, 0, stream>>>(Apack, Wspack, b_s, Sny, Snz);
    int totalA = Tcc * 16 * 8 * 64;
    k_packa<<<(totalA + 255) / 256, 256, 0, stream>>>(input, t0, Tcc, inpPack);
    hipMemsetAsync(flags, 0, 16 * 16 * 4, stream);
    k_recur<<<64, 512, 0, stream>>>(dt, Epack, Wipack, Wzpack, biasD0, biasDn,
                                    b_z, W_dt, b_dt, inpPack, Sny, Snz,
                                    Ypack, ystate, zstate, yexch, zexch, flags, t0, Tcc);
    dim3 ge(Tcc, 2);
    k_out<<<ge, 512, 0, stream>>>(Ypack, Wcpack, b_c, out, t0);
  }
}

// Round 6
// 10984.548 us; speedup vs baseline: 2.2089x; 1.4682x over previous
//
#include <hip/hip_runtime.h>
#include <stdint.h>

// ---------------------------------------------------------------------------
// LEM-style noisy RNN. T=128 x DIV=10 sequential steps, B=256, H=256.
// k_recur: 64 WGs = 16 batch-groups x 4 roles (Y0,Y1,Z0,Z1). Cross-WG y/z
// exchange via L3-coherent (sc0 sc1) loads/stores + relaxed flags -> NO L2
// invalidation/writeback (round-5's agent acquire/release trashed L2 every
// step: WRITE_SIZE 230MB/dispatch). Weights stay L2-resident all steps.
// ---------------------------------------------------------------------------

typedef __attribute__((ext_vector_type(8))) short bf16x8_t;
typedef __attribute__((ext_vector_type(4))) float f32x4_t;
typedef unsigned short u16;

__device__ __forceinline__ float bf2f(u16 b) {
  union { uint32_t u; float f; } v; v.u = ((uint32_t)b) << 16; return v.f;
}
__device__ __forceinline__ u16 f2bf(float f) {
  union { float f; uint32_t u; } v; v.f = f;
  uint32_t x = v.u;
  return (u16)((x + 0x7FFFu + ((x >> 16) & 1u)) >> 16);   // RNE
}
__device__ __forceinline__ f32x4_t mfma16(bf16x8_t a, bf16x8_t b, f32x4_t c) {
  return __builtin_amdgcn_mfma_f32_16x16x32_bf16(a, b, c, 0, 0, 0);
}
__device__ __forceinline__ float sigm(float x) { return 1.0f / (1.0f + __expf(-x)); }
__device__ __forceinline__ float tanh_f(float x) {
  float t = __expf(-2.0f * fabsf(x));
  float r = (1.0f - t) / (1.0f + t);
  return x < 0.0f ? -r : r;
}

// ---- L3-coherent (cross-XCD) transport: sc0 sc1 = bypass L1+L2 ----
__device__ __forceinline__ uint4 cload16(const void* p) {
  uint4 r;
  asm volatile("global_load_dwordx4 %0, %1, off sc0 sc1\n\ts_waitcnt vmcnt(0)"
               : "=&v"(r) : "v"(p) : "memory");
  return r;
}
__device__ __forceinline__ void cload16x2(const void* p0, const void* p1, uint4* r0, uint4* r1) {
  uint4 a, b;
  asm volatile("global_load_dwordx4 %0, %2, off sc0 sc1\n\t"
               "global_load_dwordx4 %1, %3, off sc0 sc1\n\t"
               "s_waitcnt vmcnt(0)"
               : "=&v"(a), "=&v"(b) : "v"(p0), "v"(p1) : "memory");
  *r0 = a; *r1 = b;
}
__device__ __forceinline__ uint32_t cload4(const void* p) {
  uint32_t r;
  asm volatile("global_load_dword %0, %1, off sc0 sc1\n\ts_waitcnt vmcnt(0)"
               : "=&v"(r) : "v"(p) : "memory");
  return r;
}
__device__ __forceinline__ void cstore8(void* p, uint2 v) {
  asm volatile("global_store_dwordx2 %0, %1, off sc0 sc1" :: "v"(p), "v"(v) : "memory");
}
__device__ __forceinline__ void cstore4(void* p, uint32_t v) {
  asm volatile("global_store_dword %0, %1, off sc0 sc1" :: "v"(p), "v"(v) : "memory");
}
__device__ __forceinline__ void cstore2(void* p, uint32_t v) {
  asm volatile("global_store_short %0, %1, off sc0 sc1" :: "v"(p), "v"(v) : "memory");
}
__device__ __forceinline__ void vdrain() { asm volatile("s_waitcnt vmcnt(0)" ::: "memory"); }

// MFMA 16x16x32 bf16 A-frag K-position for lane l, elem e
__device__ __forceinline__ int fragK(int l, int e) {
  return ((l >> 4) << 2) + (e & 3) + ((e >> 2) << 4);
}

// ---- JAX threefry2x32 (20 rounds) ----
__device__ __forceinline__ void threefry(uint32_t k0, uint32_t k1, uint32_t x0, uint32_t x1,
                                         uint32_t* o0, uint32_t* o1) {
  uint32_t ks2 = k0 ^ k1 ^ 0x1BD11BDAu;
  x0 += k0; x1 += k1;
#define TFR(rot) { x0 += x1; x1 = (x1 << rot) | (x1 >> (32 - rot)); x1 ^= x0; }
  TFR(13) TFR(15) TFR(26) TFR(6)   x0 += k1;  x1 += ks2 + 1u;
  TFR(17) TFR(29) TFR(16) TFR(24)  x0 += ks2; x1 += k0 + 2u;
  TFR(13) TFR(15) TFR(26) TFR(6)   x0 += k0;  x1 += k1 + 3u;
  TFR(17) TFR(29) TFR(16) TFR(24)  x0 += k1;  x1 += ks2 + 4u;
  TFR(13) TFR(15) TFR(26) TFR(6)   x0 += ks2; x1 += k0 + 5u;
#undef TFR
  *o0 = x0; *o1 = x1;
}

// bits -> N(0,1), matches jax.random.normal f32 (XLA erfinv poly)
__device__ __forceinline__ float bits2normal(uint32_t bits) {
  union { uint32_t u; float f; } cv; cv.u = 0x3F800000u | (bits >> 9);
  float f = cv.f - 1.0f;
  float u = fmaf(f, 2.0f, -0.99999994f);
  u = fmaxf(u, -0.99999994f);
  float w = -log1pf(-u * u);
  float p;
  if (w < 5.0f) {
    w = w - 2.5f;
    p = 2.81022636e-08f;
    p = fmaf(p, w, 3.43273939e-07f);
    p = fmaf(p, w, -3.5233877e-06f);
    p = fmaf(p, w, -4.39150654e-06f);
    p = fmaf(p, w, 0.00021858087f);
    p = fmaf(p, w, -0.00125372503f);
    p = fmaf(p, w, -0.00417768164f);
    p = fmaf(p, w, 0.246640727f);
    p = fmaf(p, w, 1.50140941f);
  } else {
    w = sqrtf(w) - 3.0f;
    p = -0.000200214257f;
    p = fmaf(p, w, 0.000100950558f);
    p = fmaf(p, w, 0.00134934322f);
    p = fmaf(p, w, -0.00367342844f);
    p = fmaf(p, w, 0.00573950773f);
    p = fmaf(p, w, -0.0076224613f);
    p = fmaf(p, w, 0.00943887047f);
    p = fmaf(p, w, 1.00167406f);
    p = fmaf(p, w, 2.83297682f);
  }
  return 1.41421354f * p * u;
}

// ---------------------------------------------------------------------------
__global__ void k_prep(const float* __restrict__ W_i, const float* __restrict__ W_c,
                       const float* __restrict__ b_i, const float* __restrict__ b_c,
                       float* __restrict__ Wic, float* __restrict__ bip) {
  __shared__ float wi[256];
  __shared__ float red[256];
  int o = blockIdx.x; int tid = threadIdx.x;
  wi[tid] = W_i[o * 256 + tid];
  __syncthreads();
  float acc = 0.f;
  for (int j = 0; j < 256; ++j) acc = fmaf(wi[j], W_c[j * 256 + tid], acc);
  Wic[(size_t)o * 256 + tid] = acc;
  red[tid] = wi[tid] * b_c[tid];
  __syncthreads();
  for (int s = 128; s > 0; s >>= 1) { if (tid < s) red[tid] += red[tid + s]; __syncthreads(); }
  if (tid == 0) bip[o] = b_i[o] + red[0];
}

__global__ void k_bias(const float* __restrict__ b_i, const float* __restrict__ bip,
                       const float* __restrict__ b_h,
                       float* __restrict__ biasD0, float* __restrict__ biasDn) {
  int c = blockIdx.x * 256 + threadIdx.x;
  float bh = (c < 512) ? b_h[c] : (c >= 768 ? b_h[c - 256] : 0.f);
  biasD0[c] = b_i[c] + bh;
  biasDn[c] = bip[c] + bh;
}

__global__ void k_packw(const float* __restrict__ srcA, int rowsA, const float* __restrict__ srcB,
                        u16* __restrict__ dst, int O, int K) {
  int t = blockIdx.x * blockDim.x + threadIdx.x;
  int KK = K >> 5;
  int total = (O >> 4) * KK * 64;
  if (t >= total) return;
  int l = t & 63; int kk = (t >> 6) % KK; int to = t / (64 * KK);
  int n = (to << 4) | (l & 15);
  int kb = (kk << 5) + ((l >> 4) << 2);
  const float* src = (n < rowsA) ? (srcA + (size_t)n * K) : (srcB + (size_t)(n - rowsA) * K);
  u16 out[8];
#pragma unroll
  for (int e = 0; e < 8; ++e) out[e] = f2bf(src[kb + (e & 3) + ((e >> 2) << 4)]);
  *reinterpret_cast<uint4*>(dst + (size_t)t * 8) = *reinterpret_cast<const uint4*>(out);
}

__global__ void k_packa(const float* __restrict__ inp, int t0, int Tcc, u16* __restrict__ dst) {
  int t = blockIdx.x * blockDim.x + threadIdx.x;
  int total = Tcc * 16 * 8 * 64;
  if (t >= total) return;
  int l = t & 63; int kk = (t >> 6) & 7; int mt = (t >> 9) & 15; int tl = t >> 13;
  int b = (mt << 4) | (l & 15);
  int kb = (kk << 5) + ((l >> 4) << 2);
  const float* src = inp + ((size_t)(t0 + tl) * 256 + b) * 256;
  u16 out[8];
#pragma unroll
  for (int e = 0; e < 8; ++e) out[e] = f2bf(src[kb + (e & 3) + ((e >> 2) << 4)]);
  *reinterpret_cast<uint4*>(dst + (size_t)t * 8) = *reinterpret_cast<const uint4*>(out);
}

// noise gen, JAX threefry partitionable: bits[i] = o0^o1, (o0,o1)=threefry(key, 0, i)
__global__ void k_gen(u16* __restrict__ Apack, int gstep0) {
  int sl = blockIdx.x >> 7;
  int tb = (blockIdx.x & 127) * 1024 + threadIdx.x;   // [0, 131072)
  __shared__ uint32_t kf[2];
  if (threadIdx.x == 0) {
    uint32_t o0, o1;
    threefry(0u, 1234u, 0u, (uint32_t)(gstep0 + sl), &o0, &o1);
    kf[0] = o0; kf[1] = o1;
  }
  __syncthreads();
  int e = tb & 7; int l = (tb >> 3) & 63; int kk = (tb >> 9) & 15; int mt = tb >> 13;
  int b = (mt << 4) | (l & 15);
  int c = (kk << 5) + fragK(l, e);
  uint32_t i = (uint32_t)(b * 512 + c);
  uint32_t o0, o1;
  threefry(kf[0], kf[1], 0u, i, &o0, &o1);
  Apack[(size_t)sl * 131072 + tb] = f2bf(bits2normal(o0 ^ o1));
}

// S = tanh(noise @ Ws^T + b_s), scattered into per-consumer split layouts.
__global__ __launch_bounds__(512) void k_sgemm(const u16* __restrict__ Apack,
                                               const u16* __restrict__ Wspack,
                                               const float* __restrict__ b_s,
                                               u16* __restrict__ Sny, u16* __restrict__ Snz) {
  int sl = blockIdx.x; int nq = blockIdx.y;
  int l = threadIdx.x & 63; int wv = threadIdx.x >> 6;
  const u16* Ab = Apack + (size_t)sl * 131072;
#pragma unroll 1
  for (int mtl = 0; mtl < 2; ++mtl) {
    int mt = 2 * wv + mtl;
    bf16x8_t af[16];
#pragma unroll
    for (int kk = 0; kk < 16; ++kk)
      af[kk] = *reinterpret_cast<const bf16x8_t*>(Ab + ((size_t)(mt * 16 + kk) * 64 + l) * 8);
#pragma unroll 1
    for (int ntl = 0; ntl < 8; ++ntl) {
      int nt = nq * 8 + ntl;
      f32x4_t acc = {0.f, 0.f, 0.f, 0.f};
#pragma unroll
      for (int kk = 0; kk < 16; ++kk) {
        bf16x8_t bfr = *reinterpret_cast<const bf16x8_t*>(Wspack + ((size_t)(nt * 16 + kk) * 64 + l) * 8);
        acc = mfma16(af[kk], bfr, acc);
      }
      int n = (nt << 4) | (l & 15);
      float bs = b_s[n];
#pragma unroll
      for (int r = 0; r < 4; ++r) {
        int m = (mt << 4) + ((l >> 4) << 2) + r;
        u16 v = f2bf(tanh_f(acc[r] + bs));
        int g = m >> 4, row = m & 15;
        if (n >= 256) {
          int h = n - 256; int hz = h >> 7; int h2 = h & 127;
          Snz[((((size_t)sl * 16 + g) * 2 + hz) * 512 + ((row << 5) | (h2 >> 2))) * 4 + (h2 & 3)] = v;
        } else {
          int hy = n >> 7; int wv2 = (n >> 4) & 7;
          int l2 = ((row >> 2) << 4) | (n & 15);
          Sny[((((size_t)sl * 16 + g) * 2 + hy) * 512 + (wv2 * 64 + l2)) * 4 + (row & 3)] = v;
        }
      }
    }
  }
}

// ---------------------------------------------------------------------------
// Recurrence, 64 WGs. wgid = role*16 + g. role 0/1 = Y(hy), 2/3 = Z(hz).
// Flags padded to 128B apart; all flag/exchange traffic via sc0sc1 (L3).
__global__ __launch_bounds__(512) void k_recur(
    const float* __restrict__ dt,
    const u16* __restrict__ Epack, const u16* __restrict__ Wipack, const u16* __restrict__ Wzpack,
    const float* __restrict__ biasD0, const float* __restrict__ biasDn,
    const float* __restrict__ b_z, const float* __restrict__ W_dt, const float* __restrict__ b_dt,
    const u16* __restrict__ inpPack, const u16* __restrict__ Sny, const u16* __restrict__ Snz,
    u16* __restrict__ Ypack, float* __restrict__ ystate, float* __restrict__ zstate,
    u16* __restrict__ yexch, u16* __restrict__ zexch, int* __restrict__ flags,
    int t0, int Tcc)
{
  __shared__ float G[16 * 264];      // [16 rows][2 panels x 132]
  __shared__ u16 a1b[4096];          // A-operand frags (x or y_pre)
  __shared__ u16 agb[4096];          // y_post frags
  __shared__ u16 zb[4096];           // z frags (Y only)
  __shared__ float sc[48];

  const int wgid = blockIdx.x;
  const int g = wgid & 15;
  const int role = wgid >> 4;
  const bool isY = role < 2;
  const int half = role & 1;
  const int tid = threadIdx.x;
  const int l = tid & 63;
  const int wv = tid >> 6;
  const int row = tid >> 5;
  const int hq = (tid & 31) * 4;

  int* flg = flags + g * 128;        // flag i at flg[i*32] (128B apart)
  const int nsteps = Tcc * 10;

  float zc[4];
  float yc[4];
  float bias0[2], biasn[2], bzr = 0.f;

  int tiA0, tiTh0, tiA1, tiTh1 = -1;
  if (isY) {
    tiA0 = half * 8 + wv;        tiTh0 = 64 + half * 8 + wv;
    tiA1 = 32 + half * 8 + wv;
  } else {
    tiA0 = 16 + half * 8 + wv;   tiTh0 = 80 + half * 8 + wv;
    tiA1 = 48 + half * 8 + wv;   tiTh1 = 96 + half * 8 + wv;
  }
  {
    int c0, c1;
    if (isY) { c0 = half * 128 + wv * 16 + (l & 15); c1 = 512 + c0; bzr = b_z[c0]; }
    else     { c0 = 256 + half * 128 + wv * 16 + (l & 15); c1 = c0 + 512; }
    bias0[0] = biasD0[c0]; biasn[0] = biasDn[c0];
    bias0[1] = biasD0[c1]; biasn[1] = biasDn[c1];
  }

  // ---- init: carries + Y publishes initial y_post frags (buf 0) ----
  if (isY) {
    int n = half * 128 + wv * 16 + (l & 15);
#pragma unroll
    for (int r = 0; r < 4; ++r)
      yc[r] = (t0 == 0) ? 0.f : ystate[(size_t)(g * 16 + 4 * (l >> 4) + r) * 256 + n];
    int k = half * 128 + hq;
    union { u16 h[4]; uint2 v; } pk;
#pragma unroll
    for (int j = 0; j < 4; ++j)
      pk.h[j] = (t0 == 0) ? (u16)0 : f2bf(ystate[(size_t)(g * 16 + row) * 256 + k + j]);
    int kk = k >> 5, e0 = ((k >> 4) & 1) << 2, ls = (((k & 15) >> 2) << 4) | row;
    cstore8(&yexch[((size_t)g * 2 + 1) * 4096 + kk * 512 + ls * 8 + e0], pk.v);
    vdrain();
    __syncthreads();
    if (tid == 0) cstore4(&flg[half * 32], 1u);
  } else {
    int h = half * 128 + hq;
#pragma unroll
    for (int j = 0; j < 4; ++j)
      zc[j] = (t0 == 0) ? 0.f : zstate[(size_t)(g * 16 + row) * 256 + h + j];
  }

  float wdt0 = W_dt[0], wdt1 = W_dt[1], bdt0 = b_dt[0], bdt1 = b_dt[1];

  for (int s = 0; s < nsteps; ++s) {
    int d = s % 10; int tl = s / 10;
    uint2 nsv = *reinterpret_cast<const uint2*>(
        (isY ? Sny : Snz) + ((((size_t)s * 16 + g) * 2 + half) * 512 + tid) * 4);
    if (d == 0 && tid < 16) {
      float dl = dt[(size_t)(t0 + tl) * 256 + g * 16 + tid] * 0.1f;
      sc[tid] = dl;
      sc[16 + tid] = sigm(fmaf(dl, wdt0, bdt0));
      sc[32 + tid] = sigm(fmaf(dl, wdt1, bdt1));
    }
    // ---- wait y(s) published (both halves) ----
    if (tid == 0) {
      while ((int)cload4(&flg[0]) < s + 1) __builtin_amdgcn_s_sleep(1);
    } else if (tid == 64) {
      while ((int)cload4(&flg[32]) < s + 1) __builtin_amdgcn_s_sleep(1);
    }
    __syncthreads();
    // ---- copy exchange -> LDS (coherent reads) ----
    {
      const u16* psrc = yexch + (((size_t)(s & 1) * 16 + g) * 2 + 1) * 4096 + tid * 8;
      if (d == 0) {
        uint4 rpost = cload16(psrc);
        *reinterpret_cast<uint4*>(agb + tid * 8) = rpost;
        *reinterpret_cast<uint4*>(a1b + tid * 8) =
            *reinterpret_cast<const uint4*>(inpPack + (size_t)(tl * 16 + g) * 4096 + tid * 8);
      } else {
        const u16* asrc = yexch + (((size_t)(s & 1) * 16 + g) * 2 + 0) * 4096 + tid * 8;
        uint4 r0, r1;
        cload16x2(psrc, asrc, &r0, &r1);
        *reinterpret_cast<uint4*>(agb + tid * 8) = r0;
        *reinterpret_cast<uint4*>(a1b + tid * 8) = r1;
      }
    }
    __syncthreads();

    // ---- Phase A: 2 output tiles per wave ----
    {
      bf16x8_t a1[8], ag[8];
#pragma unroll
      for (int kk = 0; kk < 8; ++kk) {
        a1[kk] = *reinterpret_cast<const bf16x8_t*>(a1b + kk * 512 + l * 8);
        ag[kk] = *reinterpret_cast<const bf16x8_t*>(agb + kk * 512 + l * 8);
      }
      const u16* TI = (d == 0) ? Wipack : Epack;
      int cpr = wv * 16 + (l & 15);
      {
        f32x4_t acc = {0.f, 0.f, 0.f, 0.f};
        const u16* bp = TI + (size_t)tiA0 * 4096 + (size_t)l * 8;
        const u16* hp = Epack + (size_t)tiTh0 * 4096 + (size_t)l * 8;
#pragma unroll
        for (int kk = 0; kk < 8; ++kk)
          acc = mfma16(a1[kk], *reinterpret_cast<const bf16x8_t*>(bp + kk * 512), acc);
#pragma unroll
        for (int kk = 0; kk < 8; ++kk)
          acc = mfma16(ag[kk], *reinterpret_cast<const bf16x8_t*>(hp + kk * 512), acc);
        float bv = (d == 0) ? bias0[0] : biasn[0];
#pragma unroll
        for (int r = 0; r < 4; ++r)
          G[(4 * (l >> 4) + r) * 264 + cpr] = acc[r] + bv;
      }
      {
        f32x4_t acc = {0.f, 0.f, 0.f, 0.f};
        const u16* bp = TI + (size_t)tiA1 * 4096 + (size_t)l * 8;
#pragma unroll
        for (int kk = 0; kk < 8; ++kk)
          acc = mfma16(a1[kk], *reinterpret_cast<const bf16x8_t*>(bp + kk * 512), acc);
        if (!isY) {
          const u16* hp = Epack + (size_t)tiTh1 * 4096 + (size_t)l * 8;
#pragma unroll
          for (int kk = 0; kk < 8; ++kk)
            acc = mfma16(ag[kk], *reinterpret_cast<const bf16x8_t*>(hp + kk * 512), acc);
        }
        float bv = (d == 0) ? bias0[1] : biasn[1];
#pragma unroll
        for (int r = 0; r < 4; ++r)
          G[(4 * (l >> 4) + r) * 264 + 132 + cpr] = acc[r] + bv;
      }
    }
    __syncthreads();

    if (!isY) {
      // ---- Phase B: z update (half), publish z frags ----
      float dl = sc[row], s2 = sc[32 + row];
      f32x4_t p2 = *reinterpret_cast<const f32x4_t*>(&G[row * 264 + hq]);
      f32x4_t iy = *reinterpret_cast<const f32x4_t*>(&G[row * 264 + 132 + hq]);
      const u16* nzp = (const u16*)&nsv;
      union { u16 h[4]; uint2 v; } zp;
#pragma unroll
      for (int j = 0; j < 4; ++j) {
        float ms = s2 * sigm(p2[j]);
        float zn = (1.0f - ms) * zc[j] + ms * tanh_f(iy[j]);
        zp.h[j] = f2bf(zn);
        zc[j] = fmaf(bf2f(nzp[j]), dl, zn);
      }
      int h = half * 128 + hq;
      int kk = h >> 5, e0 = ((h >> 4) & 1) << 2, ls = (((h & 15) >> 2) << 4) | row;
      cstore8(&zexch[((size_t)(s & 1) * 16 + g) * 4096 + kk * 512 + ls * 8 + e0], zp.v);
      vdrain();
      __syncthreads();
      if (tid == 0) cstore4(&flg[(2 + half) * 32], (uint32_t)(s + 1));
    } else {
      // ---- wait z(s), copy to LDS ----
      if (tid == 0) {
        while ((int)cload4(&flg[2 * 32]) < s + 1) __builtin_amdgcn_s_sleep(1);
      } else if (tid == 64) {
        while ((int)cload4(&flg[3 * 32]) < s + 1) __builtin_amdgcn_s_sleep(1);
      }
      __syncthreads();
      {
        uint4 rz = cload16(zexch + ((size_t)(s & 1) * 16 + g) * 4096 + tid * 8);
        *reinterpret_cast<uint4*>(zb + tid * 8) = rz;
      }
      __syncthreads();
      // ---- Phase C: W_z MFMA (half) + y update, publish y frags ----
      bf16x8_t zfr[8];
#pragma unroll
      for (int kk = 0; kk < 8; ++kk)
        zfr[kk] = *reinterpret_cast<const bf16x8_t*>(zb + kk * 512 + l * 8);
      const u16* wzp = Wzpack + (size_t)(half * 8 + wv) * 4096 + (size_t)l * 8;
      f32x4_t acc = {0.f, 0.f, 0.f, 0.f};
#pragma unroll
      for (int kk = 0; kk < 8; ++kk)
        acc = mfma16(zfr[kk], *reinterpret_cast<const bf16x8_t*>(wzp + kk * 512), acc);
      int cpr = wv * 16 + (l & 15);
      int n = half * 128 + cpr;
      int kky = n >> 5, ey = (n & 3) | (((n >> 4) & 1) << 2);
      u16* ybpre = yexch + (((size_t)((s + 1) & 1) * 16 + g) * 2 + 0) * 4096;
      u16* ybpost = ybpre + 4096;
      const u16* nyp = (const u16*)&nsv;
#pragma unroll
      for (int r = 0; r < 4; ++r) {
        int m2 = 4 * (l >> 4) + r;
        float u = acc[r] + bzr + G[m2 * 264 + 132 + cpr];
        float msb = sc[16 + m2] * sigm(G[m2 * 264 + cpr]);
        float yn = (1.0f - msb) * yc[r] + msb * tanh_f(u);
        float ypn = fmaf(bf2f(nyp[r]), sc[m2], yn);
        yc[r] = ypn;
        int lsy = (((n & 15) >> 2) << 4) | m2;
        int off = kky * 512 + lsy * 8 + ey;
        cstore2(&ybpre[off], (uint32_t)f2bf(yn));
        cstore2(&ybpost[off], (uint32_t)f2bf(ypn));
        if (d == 9)
          Ypack[(size_t)(tl * 16 + g) * 4096 + off] = f2bf(ypn);
      }
      vdrain();
      __syncthreads();
      if (tid == 0) cstore4(&flg[half * 32], (uint32_t)(s + 2));
    }
  }

  // ---- store carries ----
  if (isY) {
    int n = half * 128 + wv * 16 + (l & 15);
#pragma unroll
    for (int r = 0; r < 4; ++r)
      ystate[(size_t)(g * 16 + 4 * (l >> 4) + r) * 256 + n] = yc[r];
  } else {
    int h = half * 128 + hq;
#pragma unroll
    for (int j = 0; j < 4; ++j)
      zstate[(size_t)(g * 16 + row) * 256 + h + j] = zc[j];
  }
}

// out[t] = Y[t] @ W_c^T + b_c
__global__ __launch_bounds__(512) void k_out(const u16* __restrict__ Ypack, const u16* __restrict__ Wcpack,
                                             const float* __restrict__ b_c, float* __restrict__ out, int t0) {
  int tl = blockIdx.x; int mh = blockIdx.y;
  int l = threadIdx.x & 63; int wv = threadIdx.x >> 6;
  int mt = mh * 8 + wv;
  const u16* Ab = Ypack + (size_t)(tl * 16 + mt) * 4096 + (size_t)l * 8;
  bf16x8_t af[8];
#pragma unroll
  for (int kk = 0; kk < 8; ++kk) af[kk] = *reinterpret_cast<const bf16x8_t*>(Ab + kk * 512);
#pragma unroll 1
  for (int nt = 0; nt < 16; ++nt) {
    f32x4_t acc = {0.f, 0.f, 0.f, 0.f};
    const u16* bp = Wcpack + ((size_t)nt * 8 * 64 + l) * 8;
#pragma unroll
    for (int kk = 0; kk < 8; ++kk) {
      bf16x8_t bfr = *reinterpret_cast<const bf16x8_t*>(bp + kk * 512);
      acc = mfma16(af[kk], bfr, acc);
    }
    int n = (nt << 4) | (l & 15);
    float bc = b_c[n];
#pragma unroll
    for (int r = 0; r < 4; ++r) {
      int m = (mt << 4) + ((l >> 4) << 2) + r;
      out[((size_t)(t0 + tl) * 256 + m) * 256 + n] = acc[r] + bc;
    }
  }
}

// ---------------------------------------------------------------------------
extern "C" void kernel_launch(void* const* d_in, const int* in_sizes, int n_in,
                              void* d_out, int out_size, void* d_ws, size_t ws_size,
                              hipStream_t stream) {
  const float* input = (const float*)d_in[0];
  const float* dt    = (const float*)d_in[1];
  const float* W_i   = (const float*)d_in[2];
  const float* b_i   = (const float*)d_in[3];
  const float* W_h   = (const float*)d_in[4];
  const float* b_h   = (const float*)d_in[5];
  const float* W_z   = (const float*)d_in[6];
  const float* b_z   = (const float*)d_in[7];
  const float* W_dt  = (const float*)d_in[8];
  const float* b_dt  = (const float*)d_in[9];
  const float* W_c   = (const float*)d_in[10];
  const float* b_c   = (const float*)d_in[11];
  const float* W_s   = (const float*)d_in[12];
  const float* b_s   = (const float*)d_in[13];
  float* out = (float*)d_out;

  char* ws = (char*)d_ws;
  size_t off = 0;
  auto alloc = [&](size_t bytes) -> char* {
    char* p = ws + off; off = (off + bytes + 255) & ~(size_t)255; return p;
  };
  u16* Epack   = (u16*)alloc((size_t)112 * 8 * 512 * 2);   // [Wic;Wh] 1792x256
  u16* Wipack  = (u16*)alloc((size_t)64 * 8 * 512 * 2);
  u16* Wzpack  = (u16*)alloc((size_t)16 * 8 * 512 * 2);
  u16* Wcpack  = (u16*)alloc((size_t)16 * 8 * 512 * 2);
  u16* Wspack  = (u16*)alloc((size_t)32 * 16 * 512 * 2);
  float* bip   = (float*)alloc(1024 * 4);
  float* biasD0= (float*)alloc(1024 * 4);
  float* biasDn= (float*)alloc(1024 * 4);
  float* Wic   = (float*)alloc((size_t)1024 * 256 * 4);
  float* ystate= (float*)alloc((size_t)256 * 256 * 4);
  float* zstate= (float*)alloc((size_t)256 * 256 * 4);
  u16* yexch   = (u16*)alloc((size_t)2 * 16 * 2 * 4096 * 2);
  u16* zexch   = (u16*)alloc((size_t)2 * 16 * 4096 * 2);
  int* flags   = (int*)alloc((size_t)16 * 128 * 4);
  size_t fixed = off;
  size_t per_t = (size_t)10 * 131072 * 2      // Apack
               + (size_t)10 * 65536 * 2 * 2   // Sny + Snz
               + (size_t)16 * 8 * 512 * 2 + (size_t)16 * 8 * 512 * 2  // inpPack + Ypack
               + 4 * 256;
  int Tc = 1;
  if (ws_size > fixed + per_t) {
    size_t n = (ws_size - fixed) / per_t;
    Tc = (n > 128) ? 128 : (int)n;
  }
  if (Tc < 1) Tc = 1;
  u16* Apack   = (u16*)alloc((size_t)Tc * 10 * 131072 * 2);
  u16* Sny     = (u16*)alloc((size_t)Tc * 10 * 65536 * 2);
  u16* Snz     = (u16*)alloc((size_t)Tc * 10 * 65536 * 2);
  u16* inpPack = (u16*)alloc((size_t)Tc * 16 * 8 * 512 * 2);
  u16* Ypack   = (u16*)alloc((size_t)Tc * 16 * 8 * 512 * 2);

  k_prep<<<1024, 256, 0, stream>>>(W_i, W_c, b_i, b_c, Wic, bip);
  k_bias<<<4, 256, 0, stream>>>(b_i, bip, b_h, biasD0, biasDn);
  k_packw<<<(112 * 8 * 64) / 256, 256, 0, stream>>>(Wic, 1024, W_h, Epack, 1792, 256);
  k_packw<<<(64 * 8 * 64) / 256, 256, 0, stream>>>(W_i, 1024, (const float*)nullptr, Wipack, 1024, 256);
  k_packw<<<(16 * 8 * 64) / 256, 256, 0, stream>>>(W_z, 256, (const float*)nullptr, Wzpack, 256, 256);
  k_packw<<<(16 * 8 * 64) / 256, 256, 0, stream>>>(W_c, 256, (const float*)nullptr, Wcpack, 256, 256);
  k_packw<<<(32 * 16 * 64) / 256, 256, 0, stream>>>(W_s, 512, (const float*)nullptr, Wspack, 512, 512);

  for (int t0 = 0; t0 < 128; t0 += Tc) {
    int Tcc = (128 - t0 < Tc) ? (128 - t0) : Tc;
    int nsteps = Tcc * 10;
    k_gen<<<nsteps * 128, 1024, 0, stream>>>(Apack, t0 * 10);
    dim3 g2(nsteps, 4);
    k_sgemm<<<g2, 512, 0, stream>>>(Apack, Wspack, b_s, Sny, Snz);
    int totalA = Tcc * 16 * 8 * 64;
    k_packa<<<(totalA + 255) / 256, 256, 0, stream>>>(input, t0, Tcc, inpPack);
    hipMemsetAsync(flags, 0, 16 * 128 * 4, stream);
    k_recur<<<64, 512, 0, stream>>>(dt, Epack, Wipack, Wzpack, biasD0, biasDn,
                                    b_z, W_dt, b_dt, inpPack, Sny, Snz,
                                    Ypack, ystate, zstate, yexch, zexch, flags, t0, Tcc);
    dim3 ge(Tcc, 2);
    k_out<<<ge, 512, 0, stream>>>(Ypack, Wcpack, b_c, out, t0);
  }
}

// Round 7
// 10295.307 us; speedup vs baseline: 2.3568x; 1.0669x over previous
//
#include <hip/hip_runtime.h>
#include <stdint.h>

// ---------------------------------------------------------------------------
// LEM-style noisy RNN. T=128 x DIV=10 sequential steps, B=256, H=256.
// k_recur: 64 WGs = 16 batch-groups x 4 roles (Y0,Y1,Z0,Z1). Cross-WG y/z
// exchange via L3-coherent (sc0 sc1) transport. Round 7: producers stage
// frag-ordered payloads in LDS then publish with CONTIGUOUS 8B stores
// (round-6's scattered 2B stores caused 3x write amp + slow vmcnt drains);
// consumers poll flags from all threads (no pre-copy barrier).
// ---------------------------------------------------------------------------

typedef __attribute__((ext_vector_type(8))) short bf16x8_t;
typedef __attribute__((ext_vector_type(4))) float f32x4_t;
typedef unsigned short u16;

__device__ __forceinline__ float bf2f(u16 b) {
  union { uint32_t u; float f; } v; v.u = ((uint32_t)b) << 16; return v.f;
}
__device__ __forceinline__ u16 f2bf(float f) {
  union { float f; uint32_t u; } v; v.f = f;
  uint32_t x = v.u;
  return (u16)((x + 0x7FFFu + ((x >> 16) & 1u)) >> 16);   // RNE
}
__device__ __forceinline__ f32x4_t mfma16(bf16x8_t a, bf16x8_t b, f32x4_t c) {
  return __builtin_amdgcn_mfma_f32_16x16x32_bf16(a, b, c, 0, 0, 0);
}
__device__ __forceinline__ float sigm(float x) { return 1.0f / (1.0f + __expf(-x)); }
__device__ __forceinline__ float tanh_f(float x) {
  float t = __expf(-2.0f * fabsf(x));
  float r = (1.0f - t) / (1.0f + t);
  return x < 0.0f ? -r : r;
}

// ---- L3-coherent (cross-XCD) transport: sc0 sc1 = bypass L1+L2 ----
__device__ __forceinline__ uint4 cload16(const void* p) {
  uint4 r;
  asm volatile("global_load_dwordx4 %0, %1, off sc0 sc1\n\ts_waitcnt vmcnt(0)"
               : "=&v"(r) : "v"(p) : "memory");
  return r;
}
__device__ __forceinline__ void cload16x2(const void* p0, const void* p1, uint4* r0, uint4* r1) {
  uint4 a, b;
  asm volatile("global_load_dwordx4 %0, %2, off sc0 sc1\n\t"
               "global_load_dwordx4 %1, %3, off sc0 sc1\n\t"
               "s_waitcnt vmcnt(0)"
               : "=&v"(a), "=&v"(b) : "v"(p0), "v"(p1) : "memory");
  *r0 = a; *r1 = b;
}
__device__ __forceinline__ uint32_t cload4(const void* p) {
  uint32_t r;
  asm volatile("global_load_dword %0, %1, off sc0 sc1\n\ts_waitcnt vmcnt(0)"
               : "=&v"(r) : "v"(p) : "memory");
  return r;
}
__device__ __forceinline__ void cstore8(void* p, uint2 v) {
  asm volatile("global_store_dwordx2 %0, %1, off sc0 sc1" :: "v"(p), "v"(v) : "memory");
}
__device__ __forceinline__ void cstore4(void* p, uint32_t v) {
  asm volatile("global_store_dword %0, %1, off sc0 sc1" :: "v"(p), "v"(v) : "memory");
}
__device__ __forceinline__ void vdrain() { asm volatile("s_waitcnt vmcnt(0)" ::: "memory"); }

// MFMA 16x16x32 bf16 A-frag K-position for lane l, elem e
__device__ __forceinline__ int fragK(int l, int e) {
  return ((l >> 4) << 2) + (e & 3) + ((e >> 2) << 4);
}

// ---- JAX threefry2x32 (20 rounds) ----
__device__ __forceinline__ void threefry(uint32_t k0, uint32_t k1, uint32_t x0, uint32_t x1,
                                         uint32_t* o0, uint32_t* o1) {
  uint32_t ks2 = k0 ^ k1 ^ 0x1BD11BDAu;
  x0 += k0; x1 += k1;
#define TFR(rot) { x0 += x1; x1 = (x1 << rot) | (x1 >> (32 - rot)); x1 ^= x0; }
  TFR(13) TFR(15) TFR(26) TFR(6)   x0 += k1;  x1 += ks2 + 1u;
  TFR(17) TFR(29) TFR(16) TFR(24)  x0 += ks2; x1 += k0 + 2u;
  TFR(13) TFR(15) TFR(26) TFR(6)   x0 += k0;  x1 += k1 + 3u;
  TFR(17) TFR(29) TFR(16) TFR(24)  x0 += k1;  x1 += ks2 + 4u;
  TFR(13) TFR(15) TFR(26) TFR(6)   x0 += ks2; x1 += k0 + 5u;
#undef TFR
  *o0 = x0; *o1 = x1;
}

// bits -> N(0,1), matches jax.random.normal f32 (XLA erfinv poly)
__device__ __forceinline__ float bits2normal(uint32_t bits) {
  union { uint32_t u; float f; } cv; cv.u = 0x3F800000u | (bits >> 9);
  float f = cv.f - 1.0f;
  float u = fmaf(f, 2.0f, -0.99999994f);
  u = fmaxf(u, -0.99999994f);
  float w = -log1pf(-u * u);
  float p;
  if (w < 5.0f) {
    w = w - 2.5f;
    p = 2.81022636e-08f;
    p = fmaf(p, w, 3.43273939e-07f);
    p = fmaf(p, w, -3.5233877e-06f);
    p = fmaf(p, w, -4.39150654e-06f);
    p = fmaf(p, w, 0.00021858087f);
    p = fmaf(p, w, -0.00125372503f);
    p = fmaf(p, w, -0.00417768164f);
    p = fmaf(p, w, 0.246640727f);
    p = fmaf(p, w, 1.50140941f);
  } else {
    w = sqrtf(w) - 3.0f;
    p = -0.000200214257f;
    p = fmaf(p, w, 0.000100950558f);
    p = fmaf(p, w, 0.00134934322f);
    p = fmaf(p, w, -0.00367342844f);
    p = fmaf(p, w, 0.00573950773f);
    p = fmaf(p, w, -0.0076224613f);
    p = fmaf(p, w, 0.00943887047f);
    p = fmaf(p, w, 1.00167406f);
    p = fmaf(p, w, 2.83297682f);
  }
  return 1.41421354f * p * u;
}

// ---------------------------------------------------------------------------
__global__ void k_prep(const float* __restrict__ W_i, const float* __restrict__ W_c,
                       const float* __restrict__ b_i, const float* __restrict__ b_c,
                       float* __restrict__ Wic, float* __restrict__ bip) {
  __shared__ float wi[256];
  __shared__ float red[256];
  int o = blockIdx.x; int tid = threadIdx.x;
  wi[tid] = W_i[o * 256 + tid];
  __syncthreads();
  float acc = 0.f;
  for (int j = 0; j < 256; ++j) acc = fmaf(wi[j], W_c[j * 256 + tid], acc);
  Wic[(size_t)o * 256 + tid] = acc;
  red[tid] = wi[tid] * b_c[tid];
  __syncthreads();
  for (int s = 128; s > 0; s >>= 1) { if (tid < s) red[tid] += red[tid + s]; __syncthreads(); }
  if (tid == 0) bip[o] = b_i[o] + red[0];
}

__global__ void k_bias(const float* __restrict__ b_i, const float* __restrict__ bip,
                       const float* __restrict__ b_h,
                       float* __restrict__ biasD0, float* __restrict__ biasDn) {
  int c = blockIdx.x * 256 + threadIdx.x;
  float bh = (c < 512) ? b_h[c] : (c >= 768 ? b_h[c - 256] : 0.f);
  biasD0[c] = b_i[c] + bh;
  biasDn[c] = bip[c] + bh;
}

__global__ void k_packw(const float* __restrict__ srcA, int rowsA, const float* __restrict__ srcB,
                        u16* __restrict__ dst, int O, int K) {
  int t = blockIdx.x * blockDim.x + threadIdx.x;
  int KK = K >> 5;
  int total = (O >> 4) * KK * 64;
  if (t >= total) return;
  int l = t & 63; int kk = (t >> 6) % KK; int to = t / (64 * KK);
  int n = (to << 4) | (l & 15);
  int kb = (kk << 5) + ((l >> 4) << 2);
  const float* src = (n < rowsA) ? (srcA + (size_t)n * K) : (srcB + (size_t)(n - rowsA) * K);
  u16 out[8];
#pragma unroll
  for (int e = 0; e < 8; ++e) out[e] = f2bf(src[kb + (e & 3) + ((e >> 2) << 4)]);
  *reinterpret_cast<uint4*>(dst + (size_t)t * 8) = *reinterpret_cast<const uint4*>(out);
}

__global__ void k_packa(const float* __restrict__ inp, int t0, int Tcc, u16* __restrict__ dst) {
  int t = blockIdx.x * blockDim.x + threadIdx.x;
  int total = Tcc * 16 * 8 * 64;
  if (t >= total) return;
  int l = t & 63; int kk = (t >> 6) & 7; int mt = (t >> 9) & 15; int tl = t >> 13;
  int b = (mt << 4) | (l & 15);
  int kb = (kk << 5) + ((l >> 4) << 2);
  const float* src = inp + ((size_t)(t0 + tl) * 256 + b) * 256;
  u16 out[8];
#pragma unroll
  for (int e = 0; e < 8; ++e) out[e] = f2bf(src[kb + (e & 3) + ((e >> 2) << 4)]);
  *reinterpret_cast<uint4*>(dst + (size_t)t * 8) = *reinterpret_cast<const uint4*>(out);
}

// noise gen, JAX threefry partitionable: bits[i] = o0^o1, (o0,o1)=threefry(key, 0, i)
__global__ void k_gen(u16* __restrict__ Apack, int gstep0) {
  int sl = blockIdx.x >> 7;
  int tb = (blockIdx.x & 127) * 1024 + threadIdx.x;   // [0, 131072)
  __shared__ uint32_t kf[2];
  if (threadIdx.x == 0) {
    uint32_t o0, o1;
    threefry(0u, 1234u, 0u, (uint32_t)(gstep0 + sl), &o0, &o1);
    kf[0] = o0; kf[1] = o1;
  }
  __syncthreads();
  int e = tb & 7; int l = (tb >> 3) & 63; int kk = (tb >> 9) & 15; int mt = tb >> 13;
  int b = (mt << 4) | (l & 15);
  int c = (kk << 5) + fragK(l, e);
  uint32_t i = (uint32_t)(b * 512 + c);
  uint32_t o0, o1;
  threefry(kf[0], kf[1], 0u, i, &o0, &o1);
  Apack[(size_t)sl * 131072 + tb] = f2bf(bits2normal(o0 ^ o1));
}

// S = tanh(noise @ Ws^T + b_s), scattered into per-consumer split layouts.
__global__ __launch_bounds__(512) void k_sgemm(const u16* __restrict__ Apack,
                                               const u16* __restrict__ Wspack,
                                               const float* __restrict__ b_s,
                                               u16* __restrict__ Sny, u16* __restrict__ Snz) {
  int sl = blockIdx.x; int nq = blockIdx.y;
  int l = threadIdx.x & 63; int wv = threadIdx.x >> 6;
  const u16* Ab = Apack + (size_t)sl * 131072;
#pragma unroll 1
  for (int mtl = 0; mtl < 2; ++mtl) {
    int mt = 2 * wv + mtl;
    bf16x8_t af[16];
#pragma unroll
    for (int kk = 0; kk < 16; ++kk)
      af[kk] = *reinterpret_cast<const bf16x8_t*>(Ab + ((size_t)(mt * 16 + kk) * 64 + l) * 8);
#pragma unroll 1
    for (int ntl = 0; ntl < 8; ++ntl) {
      int nt = nq * 8 + ntl;
      f32x4_t acc = {0.f, 0.f, 0.f, 0.f};
#pragma unroll
      for (int kk = 0; kk < 16; ++kk) {
        bf16x8_t bfr = *reinterpret_cast<const bf16x8_t*>(Wspack + ((size_t)(nt * 16 + kk) * 64 + l) * 8);
        acc = mfma16(af[kk], bfr, acc);
      }
      int n = (nt << 4) | (l & 15);
      float bs = b_s[n];
#pragma unroll
      for (int r = 0; r < 4; ++r) {
        int m = (mt << 4) + ((l >> 4) << 2) + r;
        u16 v = f2bf(tanh_f(acc[r] + bs));
        int g = m >> 4, row = m & 15;
        if (n >= 256) {
          int h = n - 256; int hz = h >> 7; int h2 = h & 127;
          Snz[((((size_t)sl * 16 + g) * 2 + hz) * 512 + ((row << 5) | (h2 >> 2))) * 4 + (h2 & 3)] = v;
        } else {
          int hy = n >> 7; int wv2 = (n >> 4) & 7;
          int l2 = ((row >> 2) << 4) | (n & 15);
          Sny[((((size_t)sl * 16 + g) * 2 + hy) * 512 + (wv2 * 64 + l2)) * 4 + (row & 3)] = v;
        }
      }
    }
  }
}

// ---------------------------------------------------------------------------
// Recurrence, 64 WGs. wgid = role*16 + g. role 0/1 = Y(hy), 2/3 = Z(hz).
__global__ __launch_bounds__(512) void k_recur(
    const float* __restrict__ dt,
    const u16* __restrict__ Epack, const u16* __restrict__ Wipack, const u16* __restrict__ Wzpack,
    const float* __restrict__ biasD0, const float* __restrict__ biasDn,
    const float* __restrict__ b_z, const float* __restrict__ W_dt, const float* __restrict__ b_dt,
    const u16* __restrict__ inpPack, const u16* __restrict__ Sny, const u16* __restrict__ Snz,
    u16* __restrict__ Ypack, float* __restrict__ ystate, float* __restrict__ zstate,
    u16* __restrict__ yexch, u16* __restrict__ zexch, int* __restrict__ flags,
    int t0, int Tcc)
{
  __shared__ float G[16 * 264];      // [16 rows][2 panels x 132]
  __shared__ u16 a1b[4096];          // A-operand frags (x or y_pre); Y: pre-stage
  __shared__ u16 agb[4096];          // y_post frags; Y: post-stage
  __shared__ u16 zb[4096];           // z frags (Y: consume; Z: publish-stage)
  __shared__ float sc[48];

  const int wgid = blockIdx.x;
  const int g = wgid & 15;
  const int role = wgid >> 4;
  const bool isY = role < 2;
  const int half = role & 1;
  const int tid = threadIdx.x;
  const int l = tid & 63;
  const int wv = tid >> 6;
  const int row = tid >> 5;
  const int hq = (tid & 31) * 4;

  int* flg = flags + g * 128;        // flag i at flg[i*32] (128B apart)
  const int nsteps = Tcc * 10;
  const int hbase = half * 2048 + tid * 4;   // contiguous publish slot (u16 idx)

  float zc[4];
  float yc[4];
  float bias0[2], biasn[2], bzr = 0.f;

  int tiA0, tiTh0, tiA1, tiTh1 = -1;
  if (isY) {
    tiA0 = half * 8 + wv;        tiTh0 = 64 + half * 8 + wv;
    tiA1 = 32 + half * 8 + wv;
  } else {
    tiA0 = 16 + half * 8 + wv;   tiTh0 = 80 + half * 8 + wv;
    tiA1 = 48 + half * 8 + wv;   tiTh1 = 96 + half * 8 + wv;
  }
  {
    int c0, c1;
    if (isY) { c0 = half * 128 + wv * 16 + (l & 15); c1 = 512 + c0; bzr = b_z[c0]; }
    else     { c0 = 256 + half * 128 + wv * 16 + (l & 15); c1 = c0 + 512; }
    bias0[0] = biasD0[c0]; biasn[0] = biasDn[c0];
    bias0[1] = biasD0[c1]; biasn[1] = biasDn[c1];
  }

  // ---- init: carries + Y publishes initial y_post frags (buf 0) ----
  if (isY) {
    int n = half * 128 + wv * 16 + (l & 15);
#pragma unroll
    for (int r = 0; r < 4; ++r)
      yc[r] = (t0 == 0) ? 0.f : ystate[(size_t)(g * 16 + 4 * (l >> 4) + r) * 256 + n];
    int k = half * 128 + hq;
    union { u16 h[4]; uint2 v; } pk;
#pragma unroll
    for (int j = 0; j < 4; ++j)
      pk.h[j] = (t0 == 0) ? (u16)0 : f2bf(ystate[(size_t)(g * 16 + row) * 256 + k + j]);
    int kk = k >> 5, e0 = ((k >> 4) & 1) << 2, ls = (((k & 15) >> 2) << 4) | row;
    cstore8(&yexch[((size_t)g * 2 + 1) * 4096 + kk * 512 + ls * 8 + e0], pk.v);
    vdrain();
    __syncthreads();
    if (tid == 0) cstore4(&flg[half * 32], 1u);
  } else {
    int h = half * 128 + hq;
#pragma unroll
    for (int j = 0; j < 4; ++j)
      zc[j] = (t0 == 0) ? 0.f : zstate[(size_t)(g * 16 + row) * 256 + h + j];
  }

  float wdt0 = W_dt[0], wdt1 = W_dt[1], bdt0 = b_dt[0], bdt1 = b_dt[1];

  for (int s = 0; s < nsteps; ++s) {
    int d = s % 10; int tl = s / 10;
    uint2 nsv = *reinterpret_cast<const uint2*>(
        (isY ? Sny : Snz) + ((((size_t)s * 16 + g) * 2 + half) * 512 + tid) * 4);
    if (d == 0 && tid < 16) {
      float dl = dt[(size_t)(t0 + tl) * 256 + g * 16 + tid] * 0.1f;
      sc[tid] = dl;
      sc[16 + tid] = sigm(fmaf(dl, wdt0, bdt0));
      sc[32 + tid] = sigm(fmaf(dl, wdt1, bdt1));
    }
    // ---- all threads poll y flags (per-thread acquire via cload4 drain) ----
    while (true) {
      int f0 = (int)cload4(&flg[0]);
      int f1 = (int)cload4(&flg[32]);
      if (f0 >= s + 1 && f1 >= s + 1) break;
      __builtin_amdgcn_s_sleep(1);
    }
    // ---- copy exchange -> LDS (coherent reads) ----
    {
      const u16* psrc = yexch + (((size_t)(s & 1) * 16 + g) * 2 + 1) * 4096 + tid * 8;
      if (d == 0) {
        uint4 rpost = cload16(psrc);
        *reinterpret_cast<uint4*>(agb + tid * 8) = rpost;
        *reinterpret_cast<uint4*>(a1b + tid * 8) =
            *reinterpret_cast<const uint4*>(inpPack + (size_t)(tl * 16 + g) * 4096 + tid * 8);
      } else {
        const u16* asrc = yexch + (((size_t)(s & 1) * 16 + g) * 2 + 0) * 4096 + tid * 8;
        uint4 r0, r1;
        cload16x2(psrc, asrc, &r0, &r1);
        *reinterpret_cast<uint4*>(agb + tid * 8) = r0;
        *reinterpret_cast<uint4*>(a1b + tid * 8) = r1;
      }
    }
    __syncthreads();

    // ---- Phase A: 2 output tiles per wave ----
    {
      bf16x8_t a1[8], ag[8];
#pragma unroll
      for (int kk = 0; kk < 8; ++kk) {
        a1[kk] = *reinterpret_cast<const bf16x8_t*>(a1b + kk * 512 + l * 8);
        ag[kk] = *reinterpret_cast<const bf16x8_t*>(agb + kk * 512 + l * 8);
      }
      const u16* TI = (d == 0) ? Wipack : Epack;
      int cpr = wv * 16 + (l & 15);
      {
        f32x4_t acc = {0.f, 0.f, 0.f, 0.f};
        const u16* bp = TI + (size_t)tiA0 * 4096 + (size_t)l * 8;
        const u16* hp = Epack + (size_t)tiTh0 * 4096 + (size_t)l * 8;
#pragma unroll
        for (int kk = 0; kk < 8; ++kk)
          acc = mfma16(a1[kk], *reinterpret_cast<const bf16x8_t*>(bp + kk * 512), acc);
#pragma unroll
        for (int kk = 0; kk < 8; ++kk)
          acc = mfma16(ag[kk], *reinterpret_cast<const bf16x8_t*>(hp + kk * 512), acc);
        float bv = (d == 0) ? bias0[0] : biasn[0];
#pragma unroll
        for (int r = 0; r < 4; ++r)
          G[(4 * (l >> 4) + r) * 264 + cpr] = acc[r] + bv;
      }
      {
        f32x4_t acc = {0.f, 0.f, 0.f, 0.f};
        const u16* bp = TI + (size_t)tiA1 * 4096 + (size_t)l * 8;
#pragma unroll
        for (int kk = 0; kk < 8; ++kk)
          acc = mfma16(a1[kk], *reinterpret_cast<const bf16x8_t*>(bp + kk * 512), acc);
        if (!isY) {
          const u16* hp = Epack + (size_t)tiTh1 * 4096 + (size_t)l * 8;
#pragma unroll
          for (int kk = 0; kk < 8; ++kk)
            acc = mfma16(ag[kk], *reinterpret_cast<const bf16x8_t*>(hp + kk * 512), acc);
        }
        float bv = (d == 0) ? bias0[1] : biasn[1];
#pragma unroll
        for (int r = 0; r < 4; ++r)
          G[(4 * (l >> 4) + r) * 264 + 132 + cpr] = acc[r] + bv;
      }
    }
    __syncthreads();

    if (!isY) {
      // ---- Phase B: z update (half); stage frags in LDS; contiguous publish ----
      float dl = sc[row], s2 = sc[32 + row];
      f32x4_t p2 = *reinterpret_cast<const f32x4_t*>(&G[row * 264 + hq]);
      f32x4_t iy = *reinterpret_cast<const f32x4_t*>(&G[row * 264 + 132 + hq]);
      const u16* nzp = (const u16*)&nsv;
      union { u16 h[4]; uint2 v; } zp;
#pragma unroll
      for (int j = 0; j < 4; ++j) {
        float ms = s2 * sigm(p2[j]);
        float zn = (1.0f - ms) * zc[j] + ms * tanh_f(iy[j]);
        zp.h[j] = f2bf(zn);
        zc[j] = fmaf(bf2f(nzp[j]), dl, zn);
      }
      int h = half * 128 + hq;
      int kk = h >> 5, e0 = ((h >> 4) & 1) << 2, ls = (((h & 15) >> 2) << 4) | row;
      *reinterpret_cast<uint2*>(&zb[kk * 512 + ls * 8 + e0]) = zp.v;
      __syncthreads();
      cstore8(&zexch[((size_t)(s & 1) * 16 + g) * 4096 + hbase],
              *reinterpret_cast<const uint2*>(&zb[hbase]));
      vdrain();
      __syncthreads();
      if (tid == 0) cstore4(&flg[(2 + half) * 32], (uint32_t)(s + 1));
    } else {
      // ---- all Y threads poll z flags, copy z -> LDS ----
      while (true) {
        int f2 = (int)cload4(&flg[2 * 32]);
        int f3 = (int)cload4(&flg[3 * 32]);
        if (f2 >= s + 1 && f3 >= s + 1) break;
        __builtin_amdgcn_s_sleep(1);
      }
      {
        uint4 rz = cload16(zexch + ((size_t)(s & 1) * 16 + g) * 4096 + tid * 8);
        *reinterpret_cast<uint4*>(zb + tid * 8) = rz;
      }
      __syncthreads();
      // ---- Phase C: W_z MFMA (half) + y update; stage frags; contiguous publish ----
      bf16x8_t zfr[8];
#pragma unroll
      for (int kk = 0; kk < 8; ++kk)
        zfr[kk] = *reinterpret_cast<const bf16x8_t*>(zb + kk * 512 + l * 8);
      const u16* wzp = Wzpack + (size_t)(half * 8 + wv) * 4096 + (size_t)l * 8;
      f32x4_t acc = {0.f, 0.f, 0.f, 0.f};
#pragma unroll
      for (int kk = 0; kk < 8; ++kk)
        acc = mfma16(zfr[kk], *reinterpret_cast<const bf16x8_t*>(wzp + kk * 512), acc);
      int cpr = wv * 16 + (l & 15);
      int n = half * 128 + cpr;
      int kky = n >> 5, ey = (n & 3) | (((n >> 4) & 1) << 2);
      const u16* nyp = (const u16*)&nsv;
#pragma unroll
      for (int r = 0; r < 4; ++r) {
        int m2 = 4 * (l >> 4) + r;
        float u = acc[r] + bzr + G[m2 * 264 + 132 + cpr];
        float msb = sc[16 + m2] * sigm(G[m2 * 264 + cpr]);
        float yn = (1.0f - msb) * yc[r] + msb * tanh_f(u);
        float ypn = fmaf(bf2f(nyp[r]), sc[m2], yn);
        yc[r] = ypn;
        int lsy = (((n & 15) >> 2) << 4) | m2;
        int off = kky * 512 + lsy * 8 + ey;
        a1b[off] = f2bf(yn);      // pre-noise stage
        agb[off] = f2bf(ypn);     // post-noise stage
      }
      __syncthreads();
      {
        u16* ybpre = yexch + (((size_t)((s + 1) & 1) * 16 + g) * 2 + 0) * 4096;
        cstore8(&ybpre[hbase], *reinterpret_cast<const uint2*>(&a1b[hbase]));
        cstore8(&ybpre[4096 + hbase], *reinterpret_cast<const uint2*>(&agb[hbase]));
        if (d == 9)
          *reinterpret_cast<uint2*>(&Ypack[(size_t)(tl * 16 + g) * 4096 + hbase]) =
              *reinterpret_cast<const uint2*>(&agb[hbase]);
      }
      vdrain();
      __syncthreads();
      if (tid == 0) cstore4(&flg[half * 32], (uint32_t)(s + 2));
    }
  }

  // ---- store carries ----
  if (isY) {
    int n = half * 128 + wv * 16 + (l & 15);
#pragma unroll
    for (int r = 0; r < 4; ++r)
      ystate[(size_t)(g * 16 + 4 * (l >> 4) + r) * 256 + n] = yc[r];
  } else {
    int h = half * 128 + hq;
#pragma unroll
    for (int j = 0; j < 4; ++j)
      zstate[(size_t)(g * 16 + row) * 256 + h + j] = zc[j];
  }
}

// out[t] = Y[t] @ W_c^T + b_c
__global__ __launch_bounds__(512) void k_out(const u16* __restrict__ Ypack, const u16* __restrict__ Wcpack,
                                             const float* __restrict__ b_c, float* __restrict__ out, int t0) {
  int tl = blockIdx.x; int mh = blockIdx.y;
  int l = threadIdx.x & 63; int wv = threadIdx.x >> 6;
  int mt = mh * 8 + wv;
  const u16* Ab = Ypack + (size_t)(tl * 16 + mt) * 4096 + (size_t)l * 8;
  bf16x8_t af[8];
#pragma unroll
  for (int kk = 0; kk < 8; ++kk) af[kk] = *reinterpret_cast<const bf16x8_t*>(Ab + kk * 512);
#pragma unroll 1
  for (int nt = 0; nt < 16; ++nt) {
    f32x4_t acc = {0.f, 0.f, 0.f, 0.f};
    const u16* bp = Wcpack + ((size_t)nt * 8 * 64 + l) * 8;
#pragma unroll
    for (int kk = 0; kk < 8; ++kk) {
      bf16x8_t bfr = *reinterpret_cast<const bf16x8_t*>(bp + kk * 512);
      acc = mfma16(af[kk], bfr, acc);
    }
    int n = (nt << 4) | (l & 15);
    float bc = b_c[n];
#pragma unroll
    for (int r = 0; r < 4; ++r) {
      int m = (mt << 4) + ((l >> 4) << 2) + r;
      out[((size_t)(t0 + tl) * 256 + m) * 256 + n] = acc[r] + bc;
    }
  }
}

// ---------------------------------------------------------------------------
extern "C" void kernel_launch(void* const* d_in, const int* in_sizes, int n_in,
                              void* d_out, int out_size, void* d_ws, size_t ws_size,
                              hipStream_t stream) {
  const float* input = (const float*)d_in[0];
  const float* dt    = (const float*)d_in[1];
  const float* W_i   = (const float*)d_in[2];
  const float* b_i   = (const float*)d_in[3];
  const float* W_h   = (const float*)d_in[4];
  const float* b_h   = (const float*)d_in[5];
  const float* W_z   = (const float*)d_in[6];
  const float* b_z   = (const float*)d_in[7];
  const float* W_dt  = (const float*)d_in[8];
  const float* b_dt  = (const float*)d_in[9];
  const float* W_c   = (const float*)d_in[10];
  const float* b_c   = (const float*)d_in[11];
  const float* W_s   = (const float*)d_in[12];
  const float* b_s   = (const float*)d_in[13];
  float* out = (float*)d_out;

  char* ws = (char*)d_ws;
  size_t off = 0;
  auto alloc = [&](size_t bytes) -> char* {
    char* p = ws + off; off = (off + bytes + 255) & ~(size_t)255; return p;
  };
  u16* Epack   = (u16*)alloc((size_t)112 * 8 * 512 * 2);   // [Wic;Wh] 1792x256
  u16* Wipack  = (u16*)alloc((size_t)64 * 8 * 512 * 2);
  u16* Wzpack  = (u16*)alloc((size_t)16 * 8 * 512 * 2);
  u16* Wcpack  = (u16*)alloc((size_t)16 * 8 * 512 * 2);
  u16* Wspack  = (u16*)alloc((size_t)32 * 16 * 512 * 2);
  float* bip   = (float*)alloc(1024 * 4);
  float* biasD0= (float*)alloc(1024 * 4);
  float* biasDn= (float*)alloc(1024 * 4);
  float* Wic   = (float*)alloc((size_t)1024 * 256 * 4);
  float* ystate= (float*)alloc((size_t)256 * 256 * 4);
  float* zstate= (float*)alloc((size_t)256 * 256 * 4);
  u16* yexch   = (u16*)alloc((size_t)2 * 16 * 2 * 4096 * 2);
  u16* zexch   = (u16*)alloc((size_t)2 * 16 * 4096 * 2);
  int* flags   = (int*)alloc((size_t)16 * 128 * 4);
  size_t fixed = off;
  size_t per_t = (size_t)10 * 131072 * 2      // Apack
               + (size_t)10 * 65536 * 2 * 2   // Sny + Snz
               + (size_t)16 * 8 * 512 * 2 + (size_t)16 * 8 * 512 * 2  // inpPack + Ypack
               + 4 * 256;
  int Tc = 1;
  if (ws_size > fixed + per_t) {
    size_t n = (ws_size - fixed) / per_t;
    Tc = (n > 128) ? 128 : (int)n;
  }
  if (Tc < 1) Tc = 1;
  u16* Apack   = (u16*)alloc((size_t)Tc * 10 * 131072 * 2);
  u16* Sny     = (u16*)alloc((size_t)Tc * 10 * 65536 * 2);
  u16* Snz     = (u16*)alloc((size_t)Tc * 10 * 65536 * 2);
  u16* inpPack = (u16*)alloc((size_t)Tc * 16 * 8 * 512 * 2);
  u16* Ypack   = (u16*)alloc((size_t)Tc * 16 * 8 * 512 * 2);

  k_prep<<<1024, 256, 0, stream>>>(W_i, W_c, b_i, b_c, Wic, bip);
  k_bias<<<4, 256, 0, stream>>>(b_i, bip, b_h, biasD0, biasDn);
  k_packw<<<(112 * 8 * 64) / 256, 256, 0, stream>>>(Wic, 1024, W_h, Epack, 1792, 256);
  k_packw<<<(64 * 8 * 64) / 256, 256, 0, stream>>>(W_i, 1024, (const float*)nullptr, Wipack, 1024, 256);
  k_packw<<<(16 * 8 * 64) / 256, 256, 0, stream>>>(W_z, 256, (const float*)nullptr, Wzpack, 256, 256);
  k_packw<<<(16 * 8 * 64) / 256, 256, 0, stream>>>(W_c, 256, (const float*)nullptr, Wcpack, 256, 256);
  k_packw<<<(32 * 16 * 64) / 256, 256, 0, stream>>>(W_s, 512, (const float*)nullptr, Wspack, 512, 512);

  for (int t0 = 0; t0 < 128; t0 += Tc) {
    int Tcc = (128 - t0 < Tc) ? (128 - t0) : Tc;
    int nsteps = Tcc * 10;
    k_gen<<<nsteps * 128, 1024, 0, stream>>>(Apack, t0 * 10);
    dim3 g2(nsteps, 4);
    k_sgemm<<<g2, 512, 0, stream>>>(Apack, Wspack, b_s, Sny, Snz);
    int totalA = Tcc * 16 * 8 * 64;
    k_packa<<<(totalA + 255) / 256, 256, 0, stream>>>(input, t0, Tcc, inpPack);
    hipMemsetAsync(flags, 0, 16 * 128 * 4, stream);
    k_recur<<<64, 512, 0, stream>>>(dt, Epack, Wipack, Wzpack, biasD0, biasDn,
                                    b_z, W_dt, b_dt, inpPack, Sny, Snz,
                                    Ypack, ystate, zstate, yexch, zexch, flags, t0, Tcc);
    dim3 ge(Tcc, 2);
    k_out<<<ge, 512, 0, stream>>>(Ypack, Wcpack, b_c, out, t0);
  }
}